// Round 7
// baseline (2280.074 us; speedup 1.0000x reference)
//
#include <hip/hip_runtime.h>
#include <hip/hip_bf16.h>
#include <math.h>

typedef __attribute__((ext_vector_type(8))) short short8;
typedef __attribute__((ext_vector_type(4))) float float4_t;
typedef __attribute__((ext_vector_type(4))) unsigned int uint4_t;
typedef __attribute__((ext_vector_type(2))) unsigned int uint2_t;

#define DEV static __device__ __forceinline__

DEV unsigned short f2b(float f) {
    union { float f; unsigned int u; } x; x.f = f;
    unsigned int r = x.u + 0x7fffu + ((x.u >> 16) & 1u);
    return (unsigned short)(r >> 16);
}
DEV float b2f(unsigned short u) {
    union { unsigned int u; float f; } x; x.u = ((unsigned int)u) << 16;
    return x.f;
}
// packed 2x f32 -> 2x bf16 (v_cvt_pk_bf16_f32 on gfx950, RNE)
DEV unsigned int f2b2(float lo, float hi) {
    union { __hip_bfloat162 h; unsigned int u; } c;
    c.h = __float22bfloat162_rn(make_float2(lo, hi));
    return c.u;
}
// gelu(x) = x / (1 + 2^(a*x + b*x^3));  a = -2*0.7978845608*log2(e)
DEV float gelu_f(float x) {
    const float a = -2.3022082f, b = -0.10294372f;
    float x2 = x * x;
    float p = __builtin_fmaf(x2, b, a);          // a + b*x^2
    float e = __builtin_amdgcn_exp2f(p * x);     // 2^(a x + b x^3)
    return x * __builtin_amdgcn_rcpf(1.0f + e);
}

DEV void gld16(unsigned short* lds, const unsigned short* g) {
    __builtin_amdgcn_global_load_lds(
        (const __attribute__((address_space(1))) unsigned int*)g,
        (__attribute__((address_space(3))) unsigned int*)lds,
        16, 0, 0);
}

// ---------------------------------------------------------------------------
// Batched tiled transpose + cast: W[z] (K x N, f32) -> WT[z] (N x K, bf16)
// ---------------------------------------------------------------------------
__global__ __launch_bounds__(256) void transpose_cast_batch_kernel(
    const float* __restrict__ srcL, const float* __restrict__ srcG, int nl,
    unsigned short* __restrict__ dst0, size_t perL, int Kd, int Nd)
{
    const int z = blockIdx.z;
    const float* W = (z < nl) ? srcL + (size_t)z * Kd * Nd
                              : srcG + (size_t)(z - nl) * Kd * Nd;
    unsigned short* WT = dst0 + (size_t)z * perL;
    __shared__ float tile[32][33];
    int n0 = blockIdx.x * 32, k0 = blockIdx.y * 32;
    int tx = threadIdx.x & 31, ty = threadIdx.x >> 5;   // 32 x 8
    #pragma unroll
    for (int r = ty; r < 32; r += 8)
        tile[r][tx] = W[(size_t)(k0 + r) * Nd + n0 + tx];
    __syncthreads();
    #pragma unroll
    for (int r = ty; r < 32; r += 8)
        WT[(size_t)(n0 + r) * Kd + k0 + tx] = f2b(tile[tx][r]);
}

// ---------------------------------------------------------------------------
// copy x -> XL (f32), XG (f32), XB (bf16), float4-vectorized
// ---------------------------------------------------------------------------
__global__ __launch_bounds__(256) void copy_cast_kernel(
    const float* __restrict__ x, float* __restrict__ xl, float* __restrict__ xg,
    unsigned short* __restrict__ xb, int n4)
{
    int i = blockIdx.x * 256 + threadIdx.x;
    if (i < n4) {
        float4_t v = ((const float4_t*)x)[i];
        ((float4_t*)xl)[i] = v;
        ((float4_t*)xg)[i] = v;
        uint2_t p = { f2b2(v[0], v[1]), f2b2(v[2], v[3]) };
        ((uint2_t*)xb)[i] = p;
    }
}

// ---------------------------------------------------------------------------
// bf16 MFMA GEMM, double-buffered K-loop (round-4 addressing — the round-6
// T2 swizzle removed all 4.19M LDS bank conflicts yet REGRESSED 12% (the
// pre-swizzled global source broke sequential-lane coalescing); reverted).
// ROUND 7:
//  * XCD-chunked N-fastest block remap (m204 bijective): 1-D grid; within an
//    XCD's contiguous chunk, consecutive blocks share the A-panel on that
//    XCD's private L2 -> A re-stage latency L3(~450cy) -> L2(~200cy),
//    shrinking the per-K-step vmcnt drain that pins MfmaUtil at 20%.
//  * __launch_bounds__(256,5): VGPR 56 / LDS 32KiB fit exactly 5 blocks/CU
//    (160 KiB) -> more desynchronized blocks to cover each other's drains.
// ---------------------------------------------------------------------------
template<int BN>
__global__ __launch_bounds__(256, 5) void gemm_db_kernel(
    const unsigned short* __restrict__ A,
    const unsigned short* __restrict__ BT,
    const float* __restrict__ bias,
    const float* __restrict__ residual,
    float* __restrict__ Cf,
    unsigned short* __restrict__ Cb,
    int M, int N, int K, int act)
{
    constexpr int NI = (BN == 128) ? 4 : 2;
    __shared__ __align__(16) unsigned short As[2][128 * 32];
    __shared__ __align__(16) unsigned short Bs[2][BN * 32];
    const int tid = threadIdx.x;
    const int wave = tid >> 6, lane = tid & 63;
    const int quad = lane >> 4, l16 = lane & 15;

    // --- XCD-chunked (bijective, m204), N-fastest remap -------------------
    const int Nt = N / BN;
    const int nwg = gridDim.x;
    const int bid = blockIdx.x;
    const int q = nwg >> 3, r = nwg & 7;
    const int xcd = bid & 7, sub = bid >> 3;
    const int wgid = (xcd < r ? xcd * (q + 1) : r * (q + 1) + (xcd - r) * q) + sub;
    const int m0 = (wgid / Nt) * 128;
    const int n0 = (wgid % Nt) * BN;
    // ----------------------------------------------------------------------

    const int wm = (BN == 128) ? (wave >> 1) * 64 : wave * 32;
    const int wn = (BN == 128) ? (wave & 1) * 64 : 0;

    float4_t acc[NI][4] = {};

    const int lrow = lane >> 2;
    const int lcol = (lane & 3) * 8;
    const int r0 = wave * 16 + lrow;
    const unsigned short* Ag0 = A  + (size_t)(m0 + r0) * K + lcol;
    const unsigned short* Ag1 = A  + (size_t)(m0 + 64 + r0) * K + lcol;
    const unsigned short* Bg0 = BT + (size_t)(n0 + r0) * K + lcol;
    const unsigned short* Bg1 = (BN == 128) ? BT + (size_t)(n0 + 64 + r0) * K + lcol : nullptr;
    const int soff = (wave * 16) * 32 + lane * 8;

    const int iters = K >> 5;
    gld16(&As[0][soff], Ag0);
    gld16(&As[0][soff + 64 * 32], Ag1);
    gld16(&Bs[0][soff], Bg0);
    if (BN == 128) gld16(&Bs[0][soff + 64 * 32], Bg1);
    __syncthreads();

    for (int k = 0; k < iters; k++) {
        const int cur = k & 1;
        if (k + 1 < iters) {
            const int koff = (k + 1) << 5;
            const int nxt = cur ^ 1;
            gld16(&As[nxt][soff], Ag0 + koff);
            gld16(&As[nxt][soff + 64 * 32], Ag1 + koff);
            gld16(&Bs[nxt][soff], Bg0 + koff);
            if (BN == 128) gld16(&Bs[nxt][soff + 64 * 32], Bg1 + koff);
        }
        short8 a[NI], b[4];
        #pragma unroll
        for (int i = 0; i < NI; i++)
            a[i] = *(const short8*)(&As[cur][(wm + i * 16 + l16) * 32 + quad * 8]);
        #pragma unroll
        for (int j = 0; j < 4; j++)
            b[j] = *(const short8*)(&Bs[cur][(wn + j * 16 + l16) * 32 + quad * 8]);
        #pragma unroll
        for (int i = 0; i < NI; i++)
            #pragma unroll
            for (int j = 0; j < 4; j++)
                acc[i][j] = __builtin_amdgcn_mfma_f32_16x16x32_bf16(b[j], a[i], acc[i][j], 0, 0, 0);
        __syncthreads();
    }

    #pragma unroll
    for (int i = 0; i < NI; i++) {
        const int row = m0 + wm + i * 16 + l16;
        #pragma unroll
        for (int j = 0; j < 4; j++) {
            const int col = n0 + wn + j * 16 + quad * 4;
            const size_t idx = (size_t)row * N + col;
            float4_t v = acc[i][j] + *(const float4_t*)(bias + col);
            if (act == 1) {
                #pragma unroll
                for (int r2 = 0; r2 < 4; r2++) v[r2] = gelu_f(v[r2]);
            }
            if (residual) v += *(const float4_t*)(residual + idx);
            if (Cf) *(float4_t*)(Cf + idx) = v;
            if (Cb) {
                uint2_t o = { f2b2(v[0], v[1]), f2b2(v[2], v[3]) };
                *(uint2_t*)(Cb + idx) = o;
            }
        }
    }
}

// ---------------------------------------------------------------------------
// LayerNorm over D=512, one WAVE per row (no barriers). 4 rows/block.
// ---------------------------------------------------------------------------
__global__ __launch_bounds__(256) void ln_kernel(
    const float* __restrict__ X, const float* __restrict__ g, const float* __restrict__ b,
    float* __restrict__ Yf, unsigned short* __restrict__ Yb)
{
    const int row = blockIdx.x * 4 + (threadIdx.x >> 6);
    const int lane = threadIdx.x & 63;
    const float* xr = X + (size_t)row * 512 + lane * 8;
    float4_t v0 = *(const float4_t*)(xr);
    float4_t v1 = *(const float4_t*)(xr + 4);
    float s = v0[0] + v0[1] + v0[2] + v0[3] + v1[0] + v1[1] + v1[2] + v1[3];
    #pragma unroll
    for (int m = 32; m > 0; m >>= 1) s += __shfl_xor(s, m);
    float mu = s * (1.0f / 512.0f);
    float4_t d0 = v0 - mu, d1 = v1 - mu;
    float s2 = d0[0]*d0[0] + d0[1]*d0[1] + d0[2]*d0[2] + d0[3]*d0[3]
             + d1[0]*d1[0] + d1[1]*d1[1] + d1[2]*d1[2] + d1[3]*d1[3];
    #pragma unroll
    for (int m = 32; m > 0; m >>= 1) s2 += __shfl_xor(s2, m);
    float rs = rsqrtf(s2 * (1.0f / 512.0f) + 1e-5f);
    float4_t g0 = *(const float4_t*)(g + lane * 8);
    float4_t g1 = *(const float4_t*)(g + lane * 8 + 4);
    float4_t b0 = *(const float4_t*)(b + lane * 8);
    float4_t b1 = *(const float4_t*)(b + lane * 8 + 4);
    float4_t y0 = d0 * rs * g0 + b0;
    float4_t y1 = d1 * rs * g1 + b1;
    if (Yf) {
        float* yr = Yf + (size_t)row * 512 + lane * 8;
        *(float4_t*)(yr) = y0;
        *(float4_t*)(yr + 4) = y1;
    }
    if (Yb) {
        uint4_t pk = { f2b2(y0[0], y0[1]), f2b2(y0[2], y0[3]),
                       f2b2(y1[0], y1[1]), f2b2(y1[2], y1[3]) };
        *(uint4_t*)(Yb + (size_t)row * 512 + lane * 8) = pk;
    }
}

// ---------------------------------------------------------------------------
// Fused: v = XG + lin_interp(GA 128->4096); XG = LN(v); XBg = bf16. Wave/row.
// ---------------------------------------------------------------------------
__global__ __launch_bounds__(256) void interp_ln_kernel(
    const float* __restrict__ GA, float* __restrict__ XG,
    const float* __restrict__ g, const float* __restrict__ b,
    unsigned short* __restrict__ Yb)
{
    const int row = blockIdx.x * 4 + (threadIdx.x >> 6);
    const int lane = threadIdx.x & 63;
    const int bb = row >> 12, sfull = row & 4095;
    float pos = (sfull + 0.5f) * (128.0f / 4096.0f) - 0.5f;
    pos = fminf(fmaxf(pos, 0.0f), 127.0f);
    int i0 = (int)floorf(pos);
    int i1 = min(i0 + 1, 127);
    float w = pos - (float)i0;
    const float* ga0 = GA + ((size_t)bb * 128 + i0) * 512 + lane * 8;
    const float* ga1 = GA + ((size_t)bb * 128 + i1) * 512 + lane * 8;
    float* xr = XG + (size_t)row * 512 + lane * 8;
    float4_t v0 = *(const float4_t*)(xr)     + *(const float4_t*)(ga0)     * (1.0f - w) + *(const float4_t*)(ga1)     * w;
    float4_t v1 = *(const float4_t*)(xr + 4) + *(const float4_t*)(ga0 + 4) * (1.0f - w) + *(const float4_t*)(ga1 + 4) * w;
    float s = v0[0] + v0[1] + v0[2] + v0[3] + v1[0] + v1[1] + v1[2] + v1[3];
    #pragma unroll
    for (int m = 32; m > 0; m >>= 1) s += __shfl_xor(s, m);
    float mu = s * (1.0f / 512.0f);
    float4_t d0 = v0 - mu, d1 = v1 - mu;
    float s2 = d0[0]*d0[0] + d0[1]*d0[1] + d0[2]*d0[2] + d0[3]*d0[3]
             + d1[0]*d1[0] + d1[1]*d1[1] + d1[2]*d1[2] + d1[3]*d1[3];
    #pragma unroll
    for (int m = 32; m > 0; m >>= 1) s2 += __shfl_xor(s2, m);
    float rs = rsqrtf(s2 * (1.0f / 512.0f) + 1e-5f);
    float4_t g0 = *(const float4_t*)(g + lane * 8);
    float4_t g1 = *(const float4_t*)(g + lane * 8 + 4);
    float4_t b0 = *(const float4_t*)(b + lane * 8);
    float4_t b1 = *(const float4_t*)(b + lane * 8 + 4);
    float4_t y0 = d0 * rs * g0 + b0;
    float4_t y1 = d1 * rs * g1 + b1;
    *(float4_t*)(xr) = y0;
    *(float4_t*)(xr + 4) = y1;
    uint4_t pk = { f2b2(y0[0], y0[1]), f2b2(y0[2], y0[3]),
                   f2b2(y1[0], y1[1]), f2b2(y1[2], y1[3]) };
    *(uint4_t*)(Yb + (size_t)row * 512 + lane * 8) = pk;
}

// ---------------------------------------------------------------------------
// Local windowed attention. Block per (b, win, h). short8 loads, 256-thread
// softmax (8 lanes/row), packed 16B output stores. k padded [32][65].
// ---------------------------------------------------------------------------
__global__ __launch_bounds__(256) void local_attn_kernel(
    const unsigned short* __restrict__ QKV, const float* __restrict__ rel,
    unsigned short* __restrict__ OUT)
{
    const int blk = blockIdx.x;          // (b*128 + win)*8 + h
    const int h = blk & 7;
    const int win = (blk >> 3) & 127;
    const int b = blk >> 10;
    const int rowbase = b * 4096 + win * 32;
    __shared__ float q[32][64], k[32][65], v[32][64];
    __shared__ float sc[32][33];
    const int tid = threadIdx.x;
    const int i = tid >> 3, c = tid & 7;     // row 0..31, chunk 0..7
    {
        const unsigned short* base = QKV + (size_t)(rowbase + i) * 1536 + h * 64 + c * 8;
        short8 qv = *(const short8*)(base);
        short8 kv = *(const short8*)(base + 512);
        short8 vv = *(const short8*)(base + 1024);
        #pragma unroll
        for (int r = 0; r < 8; r++) {
            q[i][c * 8 + r] = b2f((unsigned short)qv[r]);
            k[i][c * 8 + r] = b2f((unsigned short)kv[r]);
            v[i][c * 8 + r] = b2f((unsigned short)vv[r]);
        }
    }
    __syncthreads();
    #pragma unroll
    for (int p = 0; p < 4; p++) {
        int idx = tid + p * 256;
        int si = idx >> 5, sj = idx & 31;
        float s = 0.f;
        #pragma unroll
        for (int d = 0; d < 64; d++) s += q[si][d] * k[sj][d];
        sc[si][sj] = s * 0.125f + rel[(si - sj + 31) * 8 + h];
    }
    __syncthreads();
    {
        const int j0 = c * 4;
        float a0 = sc[i][j0], a1 = sc[i][j0 + 1], a2 = sc[i][j0 + 2], a3 = sc[i][j0 + 3];
        float mx = fmaxf(fmaxf(a0, a1), fmaxf(a2, a3));
        #pragma unroll
        for (int m = 1; m < 8; m <<= 1) mx = fmaxf(mx, __shfl_xor(mx, m));
        float e0 = __expf(a0 - mx), e1 = __expf(a1 - mx), e2 = __expf(a2 - mx), e3 = __expf(a3 - mx);
        float sum = e0 + e1 + e2 + e3;
        #pragma unroll
        for (int m = 1; m < 8; m <<= 1) sum += __shfl_xor(sum, m);
        float inv = 1.0f / sum;
        sc[i][j0] = e0 * inv; sc[i][j0 + 1] = e1 * inv; sc[i][j0 + 2] = e2 * inv; sc[i][j0 + 3] = e3 * inv;
    }
    __syncthreads();
    float o[8] = {};
    #pragma unroll
    for (int j = 0; j < 32; j++) {
        float a = sc[i][j];
        #pragma unroll
        for (int r = 0; r < 8; r++) o[r] += a * v[j][c * 8 + r];
    }
    uint4_t pk = { f2b2(o[0], o[1]), f2b2(o[2], o[3]), f2b2(o[4], o[5]), f2b2(o[6], o[7]) };
    *(uint4_t*)(OUT + (size_t)(rowbase + i) * 512 + h * 64 + c * 8) = pk;
}

// ---------------------------------------------------------------------------
// Gather strided tokens for global attention (float4 + packed cvt)
// ---------------------------------------------------------------------------
__global__ __launch_bounds__(256) void gather_xs_kernel(
    const float* __restrict__ XG, unsigned short* __restrict__ XSB)
{
    int i = blockIdx.x * 256 + threadIdx.x;   // 65536 = 262144/4
    if (i < 65536) {
        int dv = (i & 127) * 4, t = (i >> 7) & 127, b = i >> 14;
        float4_t v = *(const float4_t*)(XG + ((size_t)b * 4096 + t * 32) * 512 + dv);
        uint2_t p = { f2b2(v[0], v[1]), f2b2(v[2], v[3]) };
        *(uint2_t*)(XSB + (size_t)i * 4) = p;
    }
}

// ---------------------------------------------------------------------------
// Global attention on 128 tokens/batch. Block per (b, h, qtile of 32).
// ---------------------------------------------------------------------------
__global__ __launch_bounds__(256) void global_attn_kernel(
    const unsigned short* __restrict__ GQKV, unsigned short* __restrict__ GOUT)
{
    const int blk = blockIdx.x;       // b*32 + h*4 + qt
    const int qt = blk & 3, h = (blk >> 2) & 7, b = blk >> 5;
    __shared__ unsigned short ks[128 * 64], vs[128 * 64];
    __shared__ float qs[32 * 64];
    __shared__ float sc[32 * 128];
    const int tid = threadIdx.x;
    for (int idx = tid; idx < 128 * 64; idx += 256) {
        int j = idx >> 6, d = idx & 63;
        const unsigned short* rowp = GQKV + (size_t)(b * 128 + j) * 1536 + h * 64 + d;
        ks[idx] = rowp[512];
        vs[idx] = rowp[1024];
    }
    for (int idx = tid; idx < 32 * 64; idx += 256) {
        int i = idx >> 6, d = idx & 63;
        qs[idx] = b2f(GQKV[(size_t)(b * 128 + qt * 32 + i) * 1536 + h * 64 + d]);
    }
    __syncthreads();
    for (int idx = tid; idx < 32 * 128; idx += 256) {
        int i = idx >> 7, j = idx & 127;
        float s = 0.f;
        #pragma unroll
        for (int d = 0; d < 64; d++) s += qs[i * 64 + d] * b2f(ks[j * 64 + d]);
        sc[idx] = s * 0.125f;
    }
    __syncthreads();
    if (tid < 32) {
        float mx = -1e30f;
        for (int j = 0; j < 128; j++) mx = fmaxf(mx, sc[tid * 128 + j]);
        float sum = 0.f;
        for (int j = 0; j < 128; j++) { float e = __expf(sc[tid * 128 + j] - mx); sc[tid * 128 + j] = e; sum += e; }
        float inv = 1.0f / sum;
        for (int j = 0; j < 128; j++) sc[tid * 128 + j] *= inv;
    }
    __syncthreads();
    for (int idx = tid; idx < 32 * 64; idx += 256) {
        int i = idx >> 6, d = idx & 63;
        float o = 0.f;
        for (int j = 0; j < 128; j++) o += sc[i * 128 + j] * b2f(vs[j * 64 + d]);
        GOUT[(size_t)(b * 128 + qt * 32 + i) * 512 + h * 64 + d] = f2b(o);
    }
}

// ---------------------------------------------------------------------------
// Y = X + dwconv(X): sliding-window register version.
// ---------------------------------------------------------------------------
__global__ __launch_bounds__(256) void dwconv_add_kernel(
    const float* __restrict__ X, const float* __restrict__ wconv, const float* __restrict__ bconv,
    float* __restrict__ Yf, unsigned short* __restrict__ Yb)
{
    __shared__ float wT[7][512];
    const int tid = threadIdx.x;
    for (int idx = tid; idx < 3584; idx += 256) {
        int d = idx / 7, t = idx - d * 7;       // wconv[d*7+t] -> wT[t][d]
        wT[t][d] = wconv[idx];
    }
    __syncthreads();
    const int b = blockIdx.y;
    const int s0 = blockIdx.x * 16 + (tid >> 7) * 8;   // first output s
    const int dv = (tid & 127) * 4;
    const float* Xb = X + ((size_t)b * 4096) * 512 + dv;

    float4_t win[14];
    #pragma unroll
    for (int j = 0; j < 14; j++) {
        int ss = s0 - 3 + j;
        win[j] = (ss >= 0 && ss < 4096) ? *(const float4_t*)(Xb + (size_t)ss * 512)
                                        : (float4_t){0.f, 0.f, 0.f, 0.f};
    }
    float4_t bias = *(const float4_t*)(bconv + dv);
    float4_t w[7];
    #pragma unroll
    for (int t = 0; t < 7; t++) w[t] = *(const float4_t*)(&wT[t][dv]);

    #pragma unroll
    for (int j = 0; j < 8; j++) {
        float4_t acc = bias;
        #pragma unroll
        for (int t = 0; t < 7; t++) acc += win[j + t] * w[t];
        float4_t v = win[j + 3] + acc;          // residual from window center
        size_t e = ((size_t)b * 4096 + s0 + j) * 512 + dv;
        *(float4_t*)(Yf + e) = v;
        uint2_t o = { f2b2(v[0], v[1]), f2b2(v[2], v[3]) };
        *(uint2_t*)(Yb + e) = o;
    }
}

// ---------------------------------------------------------------------------
// out = LN(w0*XL + w1*XG), softmaxed scalar weights. Wave per row.
// ---------------------------------------------------------------------------
__global__ __launch_bounds__(256) void final_kernel(
    const float* __restrict__ XL, const float* __restrict__ XG,
    const float* __restrict__ fwl, const float* __restrict__ fwg,
    const float* __restrict__ g, const float* __restrict__ bb, float* __restrict__ out)
{
    const int row = blockIdx.x * 4 + (threadIdx.x >> 6);
    const int lane = threadIdx.x & 63;
    float a = fwl[0], cc = fwg[0];
    float m = fmaxf(a, cc);
    float ea = __expf(a - m), ec = __expf(cc - m);
    float w0 = ea / (ea + ec), w1 = ec / (ea + ec);
    const float* xlr = XL + (size_t)row * 512 + lane * 8;
    const float* xgr = XG + (size_t)row * 512 + lane * 8;
    float4_t v0 = *(const float4_t*)(xlr)     * w0 + *(const float4_t*)(xgr)     * w1;
    float4_t v1 = *(const float4_t*)(xlr + 4) * w0 + *(const float4_t*)(xgr + 4) * w1;
    float s = v0[0] + v0[1] + v0[2] + v0[3] + v1[0] + v1[1] + v1[2] + v1[3];
    #pragma unroll
    for (int mm = 32; mm > 0; mm >>= 1) s += __shfl_xor(s, mm);
    float mu = s * (1.0f / 512.0f);
    float4_t d0 = v0 - mu, d1 = v1 - mu;
    float s2 = d0[0]*d0[0] + d0[1]*d0[1] + d0[2]*d0[2] + d0[3]*d0[3]
             + d1[0]*d1[0] + d1[1]*d1[1] + d1[2]*d1[2] + d1[3]*d1[3];
    #pragma unroll
    for (int mm = 32; mm > 0; mm >>= 1) s2 += __shfl_xor(s2, mm);
    float rs = rsqrtf(s2 * (1.0f / 512.0f) + 1e-5f);
    float4_t g0 = *(const float4_t*)(g + lane * 8);
    float4_t g1 = *(const float4_t*)(g + lane * 8 + 4);
    float4_t b0 = *(const float4_t*)(bb + lane * 8);
    float4_t b1 = *(const float4_t*)(bb + lane * 8 + 4);
    float* orow = out + (size_t)row * 512 + lane * 8;
    *(float4_t*)(orow)     = d0 * rs * g0 + b0;
    *(float4_t*)(orow + 4) = d1 * rs * g1 + b1;
}

// ---------------------------------------------------------------------------
extern "C" void kernel_launch(void* const* d_in, const int* in_sizes, int n_in,
                              void* d_out, int out_size, void* d_ws, size_t ws_size,
                              hipStream_t stream)
{
    (void)in_sizes; (void)n_in; (void)out_size; (void)ws_size;
    const float* x       = (const float*)d_in[0];
    const float* lqkv_w  = (const float*)d_in[1];
    const float* lqkv_b  = (const float*)d_in[2];
    const float* lproj_w = (const float*)d_in[3];
    const float* lproj_b = (const float*)d_in[4];
    const float* lrel    = (const float*)d_in[5];
    const float* lconv_w = (const float*)d_in[6];
    const float* lconv_b = (const float*)d_in[7];
    const float* ln1_g   = (const float*)d_in[8];
    const float* ln1_b   = (const float*)d_in[9];
    const float* lffn_w1 = (const float*)d_in[10];
    const float* lffn_b1 = (const float*)d_in[11];
    const float* lffn_w2 = (const float*)d_in[12];
    const float* lffn_b2 = (const float*)d_in[13];
    const float* ln2_g   = (const float*)d_in[14];
    const float* ln2_b   = (const float*)d_in[15];
    const float* gqkv_w  = (const float*)d_in[16];
    const float* gqkv_b  = (const float*)d_in[17];
    const float* gproj_w = (const float*)d_in[18];
    const float* gproj_b = (const float*)d_in[19];
    const float* gn1_g   = (const float*)d_in[20];
    const float* gn1_b   = (const float*)d_in[21];
    const float* gffn_w1 = (const float*)d_in[22];
    const float* gffn_b1 = (const float*)d_in[23];
    const float* gffn_w2 = (const float*)d_in[24];
    const float* gffn_b2 = (const float*)d_in[25];
    const float* gn2_g   = (const float*)d_in[26];
    const float* gn2_b   = (const float*)d_in[27];
    const float* fw_local  = (const float*)d_in[28];
    const float* fw_global = (const float*)d_in[29];
    const float* fn_g    = (const float*)d_in[30];
    const float* fn_b    = (const float*)d_in[31];
    float* out = (float*)d_out;

    const int Btot = 4 * 4096;     // 16384 token rows
    const int nel = Btot * 512;    // 8388608

    char* wsb = (char*)d_ws;
    size_t off = 0;
    auto alloc = [&](size_t bytes) -> void* {
        void* p = wsb + off;
        off = (off + bytes + 255) & ~(size_t)255;
        return p;
    };
    float*          XL   = (float*)alloc((size_t)nel * 4);
    float*          XG   = (float*)alloc((size_t)nel * 4);
    float*          TMP  = (float*)alloc((size_t)nel * 4);
    unsigned short* XBl  = (unsigned short*)alloc((size_t)nel * 2);
    unsigned short* XBg  = (unsigned short*)alloc((size_t)nel * 2);
    unsigned short* AOUT = (unsigned short*)alloc((size_t)nel * 2);
    unsigned short* BIG  = (unsigned short*)alloc((size_t)Btot * 2048 * 2);
    unsigned short* WT   = (unsigned short*)alloc((size_t)22020096 * 2);
    unsigned short* XSB  = (unsigned short*)alloc((size_t)512 * 512 * 2);
    unsigned short* GQKV = (unsigned short*)alloc((size_t)512 * 1536 * 2);
    unsigned short* GOUT = (unsigned short*)alloc((size_t)512 * 512 * 2);
    float*          GA   = (float*)alloc((size_t)512 * 512 * 4);

    const size_t perL = 3145728;   // bf16 elems of transposed weights per layer
    {
        dim3 blk(256);
        transpose_cast_batch_kernel<<<dim3(1536/32, 512/32, 7), blk, 0, stream>>>(
            lqkv_w, gqkv_w, 4, WT, perL, 512, 1536);
        transpose_cast_batch_kernel<<<dim3(512/32, 512/32, 7), blk, 0, stream>>>(
            lproj_w, gproj_w, 4, WT + 786432, perL, 512, 512);
        transpose_cast_batch_kernel<<<dim3(2048/32, 512/32, 7), blk, 0, stream>>>(
            lffn_w1, gffn_w1, 4, WT + 786432 + 262144, perL, 512, 2048);
        transpose_cast_batch_kernel<<<dim3(512/32, 2048/32, 7), blk, 0, stream>>>(
            lffn_w2, gffn_w2, 4, WT + 786432 + 262144 + 1048576, perL, 2048, 512);
    }

    copy_cast_kernel<<<dim3(nel / 1024), dim3(256), 0, stream>>>(x, XL, XG, XBl, nel / 4);

    // 1-D grid; kernel does XCD-chunked, N-fastest remap internally.
    auto gemm = [&](const unsigned short* A_, const unsigned short* BT_, const float* bias_,
                    const float* res_, float* Cf_, unsigned short* Cb_,
                    int M_, int N_, int K_, int act_) {
        if (N_ >= 1024 || M_ >= 1024) {
            gemm_db_kernel<128><<<dim3((M_ / 128) * (N_ / 128)), dim3(256), 0, stream>>>(
                A_, BT_, bias_, res_, Cf_, Cb_, M_, N_, K_, act_);
        } else {
            gemm_db_kernel<64><<<dim3((M_ / 128) * (N_ / 64)), dim3(256), 0, stream>>>(
                A_, BT_, bias_, res_, Cf_, Cb_, M_, N_, K_, act_);
        }
    };

    // ---------------- local branch: 4 layers ----------------
    for (int i = 0; i < 4; i++) {
        unsigned short* base  = WT + (size_t)i * perL;
        unsigned short* qkvT  = base;
        unsigned short* projT = base + 786432;
        unsigned short* w1T   = base + 786432 + 262144;
        unsigned short* w2T   = base + 786432 + 262144 + 1048576;

        gemm(XBl, qkvT, lqkv_b + i * 1536, nullptr, nullptr, BIG, Btot, 1536, 512, 0);
        local_attn_kernel<<<dim3(4096), dim3(256), 0, stream>>>(BIG, lrel + (size_t)i * 63 * 8, AOUT);
        gemm(AOUT, projT, lproj_b + i * 512, XL, TMP, nullptr, Btot, 512, 512, 0);
        ln_kernel<<<dim3(Btot / 4), dim3(256), 0, stream>>>(TMP, ln1_g + i * 512, ln1_b + i * 512, XL, (unsigned short*)nullptr);
        dwconv_add_kernel<<<dim3(256, 4), dim3(256), 0, stream>>>(XL, lconv_w + (size_t)i * 512 * 7, lconv_b + i * 512, TMP, XBl);
        gemm(XBl, w1T, lffn_b1 + i * 2048, nullptr, nullptr, BIG, Btot, 2048, 512, 1);
        gemm(BIG, w2T, lffn_b2 + i * 512, TMP, TMP, nullptr, Btot, 512, 2048, 0);
        ln_kernel<<<dim3(Btot / 4), dim3(256), 0, stream>>>(TMP, ln2_g + i * 512, ln2_b + i * 512, XL, XBl);
    }

    // ---------------- global branch: 3 layers ----------------
    for (int i = 0; i < 3; i++) {
        unsigned short* base  = WT + (size_t)(4 + i) * perL;
        unsigned short* qkvT  = base;
        unsigned short* projT = base + 786432;
        unsigned short* w1T   = base + 786432 + 262144;
        unsigned short* w2T   = base + 786432 + 262144 + 1048576;

        gather_xs_kernel<<<dim3(256), dim3(256), 0, stream>>>(XG, XSB);
        gemm(XSB, qkvT, gqkv_b + i * 1536, nullptr, nullptr, GQKV, 512, 1536, 512, 0);
        global_attn_kernel<<<dim3(128), dim3(256), 0, stream>>>(GQKV, GOUT);
        gemm(GOUT, projT, gproj_b + i * 512, nullptr, GA, nullptr, 512, 512, 512, 0);
        interp_ln_kernel<<<dim3(Btot / 4), dim3(256), 0, stream>>>(GA, XG, gn1_g + i * 512, gn1_b + i * 512, XBg);
        gemm(XBg, w1T, gffn_b1 + i * 2048, nullptr, nullptr, BIG, Btot, 2048, 512, 1);
        gemm(BIG, w2T, gffn_b2 + i * 512, XG, TMP, nullptr, Btot, 512, 2048, 0);
        ln_kernel<<<dim3(Btot / 4), dim3(256), 0, stream>>>(TMP, gn2_g + i * 512, gn2_b + i * 512, XG, XBg);
    }

    final_kernel<<<dim3(Btot / 4), dim3(256), 0, stream>>>(XL, XG, fw_local, fw_global, fn_g, fn_b, out);
}

// Round 8
// 1835.304 us; speedup vs baseline: 1.2423x; 1.2423x over previous
//
#include <hip/hip_runtime.h>
#include <hip/hip_bf16.h>
#include <math.h>

typedef __attribute__((ext_vector_type(8))) short short8;
typedef __attribute__((ext_vector_type(4))) float float4_t;
typedef __attribute__((ext_vector_type(4))) unsigned int uint4_t;
typedef __attribute__((ext_vector_type(2))) unsigned int uint2_t;

#define DEV static __device__ __forceinline__

DEV unsigned short f2b(float f) {
    union { float f; unsigned int u; } x; x.f = f;
    unsigned int r = x.u + 0x7fffu + ((x.u >> 16) & 1u);
    return (unsigned short)(r >> 16);
}
DEV float b2f(unsigned short u) {
    union { unsigned int u; float f; } x; x.u = ((unsigned int)u) << 16;
    return x.f;
}
// packed 2x f32 -> 2x bf16 (v_cvt_pk_bf16_f32 on gfx950, RNE)
DEV unsigned int f2b2(float lo, float hi) {
    union { __hip_bfloat162 h; unsigned int u; } c;
    c.h = __float22bfloat162_rn(make_float2(lo, hi));
    return c.u;
}
// gelu(x) = x / (1 + 2^(a*x + b*x^3));  a = -2*0.7978845608*log2(e)
DEV float gelu_f(float x) {
    const float a = -2.3022082f, b = -0.10294372f;
    float x2 = x * x;
    float p = __builtin_fmaf(x2, b, a);          // a + b*x^2
    float e = __builtin_amdgcn_exp2f(p * x);     // 2^(a x + b x^3)
    return x * __builtin_amdgcn_rcpf(1.0f + e);
}

// ---------------------------------------------------------------------------
// Batched tiled transpose + cast: W[z] (K x N, f32) -> WT[z] (N x K, bf16)
// ---------------------------------------------------------------------------
__global__ __launch_bounds__(256) void transpose_cast_batch_kernel(
    const float* __restrict__ srcL, const float* __restrict__ srcG, int nl,
    unsigned short* __restrict__ dst0, size_t perL, int Kd, int Nd)
{
    const int z = blockIdx.z;
    const float* W = (z < nl) ? srcL + (size_t)z * Kd * Nd
                              : srcG + (size_t)(z - nl) * Kd * Nd;
    unsigned short* WT = dst0 + (size_t)z * perL;
    __shared__ float tile[32][33];
    int n0 = blockIdx.x * 32, k0 = blockIdx.y * 32;
    int tx = threadIdx.x & 31, ty = threadIdx.x >> 5;   // 32 x 8
    #pragma unroll
    for (int r = ty; r < 32; r += 8)
        tile[r][tx] = W[(size_t)(k0 + r) * Nd + n0 + tx];
    __syncthreads();
    #pragma unroll
    for (int r = ty; r < 32; r += 8)
        WT[(size_t)(n0 + r) * Kd + k0 + tx] = f2b(tile[tx][r]);
}

// ---------------------------------------------------------------------------
// copy x -> XL (f32), XG (f32), XB (bf16), float4-vectorized
// ---------------------------------------------------------------------------
__global__ __launch_bounds__(256) void copy_cast_kernel(
    const float* __restrict__ x, float* __restrict__ xl, float* __restrict__ xg,
    unsigned short* __restrict__ xb, int n4)
{
    int i = blockIdx.x * 256 + threadIdx.x;
    if (i < n4) {
        float4_t v = ((const float4_t*)x)[i];
        ((float4_t*)xl)[i] = v;
        ((float4_t*)xg)[i] = v;
        uint2_t p = { f2b2(v[0], v[1]), f2b2(v[2], v[3]) };
        ((uint2_t*)xb)[i] = p;
    }
}

// ---------------------------------------------------------------------------
// bf16 MFMA GEMM — ROUND 8: REGISTER-STAGED pipeline (T14 structure).
// Every __syncthreads() force-drains global_load_lds (vmcnt(0)) — that drain
// is the measured ~80% stall (rounds 1/4/5/6/7 all pin MfmaUtil ~20%; the
// asm-barrier escape hangs the device). Plain global_load -> VGPR is NOT
// drained at barriers (only LDS writes have cross-wave visibility; evidence:
// learn_hip m99/m100 reg-staged dbuf ran 839-890 TF). So stage via
// global->reg->ds_write with prefetch distance 2:
//   iter k: ds_write tile k+1 (regs; vmcnt wait covered by iter k-1 compute)
//           issue global loads tile k+2 -> regs
//           ds_read frags tile k from buf[cur]; MFMA
//           __syncthreads()   // lgkm-only drain (~60cy), not ~400cy vmem
// Addressing/grid/epilogue identical to the round-4 baseline (1874 us).
// ---------------------------------------------------------------------------
template<int BN>
__global__ __launch_bounds__(256, 4) void gemm_rp_kernel(
    const unsigned short* __restrict__ A,
    const unsigned short* __restrict__ BT,
    const float* __restrict__ bias,
    const float* __restrict__ residual,
    float* __restrict__ Cf,
    unsigned short* __restrict__ Cb,
    int M, int N, int K, int act)
{
    constexpr int NI = (BN == 128) ? 4 : 2;
    __shared__ __align__(16) unsigned short As[2][128 * 32];
    __shared__ __align__(16) unsigned short Bs[2][BN * 32];
    const int tid = threadIdx.x;
    const int wave = tid >> 6, lane = tid & 63;
    const int quad = lane >> 4, l16 = lane & 15;
    const int m0 = blockIdx.x * 128, n0 = blockIdx.y * BN;
    const int wm = (BN == 128) ? (wave >> 1) * 64 : wave * 32;
    const int wn = (BN == 128) ? (wave & 1) * 64 : 0;

    float4_t acc[NI][4] = {};

    const int lrow = lane >> 2;
    const int lcol = (lane & 3) * 8;
    const int r0 = wave * 16 + lrow;
    const unsigned short* Ag0 = A  + (size_t)(m0 + r0) * K + lcol;
    const unsigned short* Ag1 = A  + (size_t)(m0 + 64 + r0) * K + lcol;
    const unsigned short* Bg0 = BT + (size_t)(n0 + r0) * K + lcol;
    const unsigned short* Bg1 = (BN == 128) ? BT + (size_t)(n0 + 64 + r0) * K + lcol : nullptr;
    // soff = row*32 + col for row = wave*16 + (lane>>2), col = (lane&3)*8
    const int soff = (wave * 16) * 32 + lane * 8;

    const int iters = K >> 5;

    uint4_t rA0, rA1, rB0, rB1;
    // ---- prologue: tile 0 -> regs -> buf0; tile 1 -> regs ----
    rA0 = *(const uint4_t*)(Ag0);
    rA1 = *(const uint4_t*)(Ag1);
    rB0 = *(const uint4_t*)(Bg0);
    if (BN == 128) rB1 = *(const uint4_t*)(Bg1);
    *(uint4_t*)(&As[0][soff])           = rA0;
    *(uint4_t*)(&As[0][soff + 64 * 32]) = rA1;
    *(uint4_t*)(&Bs[0][soff])           = rB0;
    if (BN == 128) *(uint4_t*)(&Bs[0][soff + 64 * 32]) = rB1;
    if (iters > 1) {
        rA0 = *(const uint4_t*)(Ag0 + 32);
        rA1 = *(const uint4_t*)(Ag1 + 32);
        rB0 = *(const uint4_t*)(Bg0 + 32);
        if (BN == 128) rB1 = *(const uint4_t*)(Bg1 + 32);
    }
    __syncthreads();

    for (int k = 0; k < iters; k++) {
        const int cur = k & 1;
        if (k + 1 < iters) {
            const int nxt = cur ^ 1;
            // ds_write tile k+1 (compiler waits vmcnt for these regs here —
            // latency was covered by iter k-1's compute + barrier)
            *(uint4_t*)(&As[nxt][soff])           = rA0;
            *(uint4_t*)(&As[nxt][soff + 64 * 32]) = rA1;
            *(uint4_t*)(&Bs[nxt][soff])           = rB0;
            if (BN == 128) *(uint4_t*)(&Bs[nxt][soff + 64 * 32]) = rB1;
            if (k + 2 < iters) {
                const int koff = (k + 2) << 5;
                rA0 = *(const uint4_t*)(Ag0 + koff);
                rA1 = *(const uint4_t*)(Ag1 + koff);
                rB0 = *(const uint4_t*)(Bg0 + koff);
                if (BN == 128) rB1 = *(const uint4_t*)(Bg1 + koff);
            }
        }
        short8 a[NI], b[4];
        #pragma unroll
        for (int i = 0; i < NI; i++)
            a[i] = *(const short8*)(&As[cur][(wm + i * 16 + l16) * 32 + quad * 8]);
        #pragma unroll
        for (int j = 0; j < 4; j++)
            b[j] = *(const short8*)(&Bs[cur][(wn + j * 16 + l16) * 32 + quad * 8]);
        #pragma unroll
        for (int i = 0; i < NI; i++)
            #pragma unroll
            for (int j = 0; j < 4; j++)
                acc[i][j] = __builtin_amdgcn_mfma_f32_16x16x32_bf16(b[j], a[i], acc[i][j], 0, 0, 0);
        __syncthreads();
    }

    #pragma unroll
    for (int i = 0; i < NI; i++) {
        const int row = m0 + wm + i * 16 + l16;
        #pragma unroll
        for (int j = 0; j < 4; j++) {
            const int col = n0 + wn + j * 16 + quad * 4;
            const size_t idx = (size_t)row * N + col;
            float4_t v = acc[i][j] + *(const float4_t*)(bias + col);
            if (act == 1) {
                #pragma unroll
                for (int r2 = 0; r2 < 4; r2++) v[r2] = gelu_f(v[r2]);
            }
            if (residual) v += *(const float4_t*)(residual + idx);
            if (Cf) *(float4_t*)(Cf + idx) = v;
            if (Cb) {
                uint2_t o = { f2b2(v[0], v[1]), f2b2(v[2], v[3]) };
                *(uint2_t*)(Cb + idx) = o;
            }
        }
    }
}

// ---------------------------------------------------------------------------
// LayerNorm over D=512, one WAVE per row (no barriers). 4 rows/block.
// ---------------------------------------------------------------------------
__global__ __launch_bounds__(256) void ln_kernel(
    const float* __restrict__ X, const float* __restrict__ g, const float* __restrict__ b,
    float* __restrict__ Yf, unsigned short* __restrict__ Yb)
{
    const int row = blockIdx.x * 4 + (threadIdx.x >> 6);
    const int lane = threadIdx.x & 63;
    const float* xr = X + (size_t)row * 512 + lane * 8;
    float4_t v0 = *(const float4_t*)(xr);
    float4_t v1 = *(const float4_t*)(xr + 4);
    float s = v0[0] + v0[1] + v0[2] + v0[3] + v1[0] + v1[1] + v1[2] + v1[3];
    #pragma unroll
    for (int m = 32; m > 0; m >>= 1) s += __shfl_xor(s, m);
    float mu = s * (1.0f / 512.0f);
    float4_t d0 = v0 - mu, d1 = v1 - mu;
    float s2 = d0[0]*d0[0] + d0[1]*d0[1] + d0[2]*d0[2] + d0[3]*d0[3]
             + d1[0]*d1[0] + d1[1]*d1[1] + d1[2]*d1[2] + d1[3]*d1[3];
    #pragma unroll
    for (int m = 32; m > 0; m >>= 1) s2 += __shfl_xor(s2, m);
    float rs = rsqrtf(s2 * (1.0f / 512.0f) + 1e-5f);
    float4_t g0 = *(const float4_t*)(g + lane * 8);
    float4_t g1 = *(const float4_t*)(g + lane * 8 + 4);
    float4_t b0 = *(const float4_t*)(b + lane * 8);
    float4_t b1 = *(const float4_t*)(b + lane * 8 + 4);
    float4_t y0 = d0 * rs * g0 + b0;
    float4_t y1 = d1 * rs * g1 + b1;
    if (Yf) {
        float* yr = Yf + (size_t)row * 512 + lane * 8;
        *(float4_t*)(yr) = y0;
        *(float4_t*)(yr + 4) = y1;
    }
    if (Yb) {
        uint4_t pk = { f2b2(y0[0], y0[1]), f2b2(y0[2], y0[3]),
                       f2b2(y1[0], y1[1]), f2b2(y1[2], y1[3]) };
        *(uint4_t*)(Yb + (size_t)row * 512 + lane * 8) = pk;
    }
}

// ---------------------------------------------------------------------------
// Fused: v = XG + lin_interp(GA 128->4096); XG = LN(v); XBg = bf16. Wave/row.
// ---------------------------------------------------------------------------
__global__ __launch_bounds__(256) void interp_ln_kernel(
    const float* __restrict__ GA, float* __restrict__ XG,
    const float* __restrict__ g, const float* __restrict__ b,
    unsigned short* __restrict__ Yb)
{
    const int row = blockIdx.x * 4 + (threadIdx.x >> 6);
    const int lane = threadIdx.x & 63;
    const int bb = row >> 12, sfull = row & 4095;
    float pos = (sfull + 0.5f) * (128.0f / 4096.0f) - 0.5f;
    pos = fminf(fmaxf(pos, 0.0f), 127.0f);
    int i0 = (int)floorf(pos);
    int i1 = min(i0 + 1, 127);
    float w = pos - (float)i0;
    const float* ga0 = GA + ((size_t)bb * 128 + i0) * 512 + lane * 8;
    const float* ga1 = GA + ((size_t)bb * 128 + i1) * 512 + lane * 8;
    float* xr = XG + (size_t)row * 512 + lane * 8;
    float4_t v0 = *(const float4_t*)(xr)     + *(const float4_t*)(ga0)     * (1.0f - w) + *(const float4_t*)(ga1)     * w;
    float4_t v1 = *(const float4_t*)(xr + 4) + *(const float4_t*)(ga0 + 4) * (1.0f - w) + *(const float4_t*)(ga1 + 4) * w;
    float s = v0[0] + v0[1] + v0[2] + v0[3] + v1[0] + v1[1] + v1[2] + v1[3];
    #pragma unroll
    for (int m = 32; m > 0; m >>= 1) s += __shfl_xor(s, m);
    float mu = s * (1.0f / 512.0f);
    float4_t d0 = v0 - mu, d1 = v1 - mu;
    float s2 = d0[0]*d0[0] + d0[1]*d0[1] + d0[2]*d0[2] + d0[3]*d0[3]
             + d1[0]*d1[0] + d1[1]*d1[1] + d1[2]*d1[2] + d1[3]*d1[3];
    #pragma unroll
    for (int m = 32; m > 0; m >>= 1) s2 += __shfl_xor(s2, m);
    float rs = rsqrtf(s2 * (1.0f / 512.0f) + 1e-5f);
    float4_t g0 = *(const float4_t*)(g + lane * 8);
    float4_t g1 = *(const float4_t*)(g + lane * 8 + 4);
    float4_t b0 = *(const float4_t*)(b + lane * 8);
    float4_t b1 = *(const float4_t*)(b + lane * 8 + 4);
    float4_t y0 = d0 * rs * g0 + b0;
    float4_t y1 = d1 * rs * g1 + b1;
    *(float4_t*)(xr) = y0;
    *(float4_t*)(xr + 4) = y1;
    uint4_t pk = { f2b2(y0[0], y0[1]), f2b2(y0[2], y0[3]),
                   f2b2(y1[0], y1[1]), f2b2(y1[2], y1[3]) };
    *(uint4_t*)(Yb + (size_t)row * 512 + lane * 8) = pk;
}

// ---------------------------------------------------------------------------
// Local windowed attention. Block per (b, win, h). short8 loads, 256-thread
// softmax (8 lanes/row), packed 16B output stores. k padded [32][65].
// ---------------------------------------------------------------------------
__global__ __launch_bounds__(256) void local_attn_kernel(
    const unsigned short* __restrict__ QKV, const float* __restrict__ rel,
    unsigned short* __restrict__ OUT)
{
    const int blk = blockIdx.x;          // (b*128 + win)*8 + h
    const int h = blk & 7;
    const int win = (blk >> 3) & 127;
    const int b = blk >> 10;
    const int rowbase = b * 4096 + win * 32;
    __shared__ float q[32][64], k[32][65], v[32][64];
    __shared__ float sc[32][33];
    const int tid = threadIdx.x;
    const int i = tid >> 3, c = tid & 7;     // row 0..31, chunk 0..7
    {
        const unsigned short* base = QKV + (size_t)(rowbase + i) * 1536 + h * 64 + c * 8;
        short8 qv = *(const short8*)(base);
        short8 kv = *(const short8*)(base + 512);
        short8 vv = *(const short8*)(base + 1024);
        #pragma unroll
        for (int r = 0; r < 8; r++) {
            q[i][c * 8 + r] = b2f((unsigned short)qv[r]);
            k[i][c * 8 + r] = b2f((unsigned short)kv[r]);
            v[i][c * 8 + r] = b2f((unsigned short)vv[r]);
        }
    }
    __syncthreads();
    #pragma unroll
    for (int p = 0; p < 4; p++) {
        int idx = tid + p * 256;
        int si = idx >> 5, sj = idx & 31;
        float s = 0.f;
        #pragma unroll
        for (int d = 0; d < 64; d++) s += q[si][d] * k[sj][d];
        sc[si][sj] = s * 0.125f + rel[(si - sj + 31) * 8 + h];
    }
    __syncthreads();
    {
        const int j0 = c * 4;
        float a0 = sc[i][j0], a1 = sc[i][j0 + 1], a2 = sc[i][j0 + 2], a3 = sc[i][j0 + 3];
        float mx = fmaxf(fmaxf(a0, a1), fmaxf(a2, a3));
        #pragma unroll
        for (int m = 1; m < 8; m <<= 1) mx = fmaxf(mx, __shfl_xor(mx, m));
        float e0 = __expf(a0 - mx), e1 = __expf(a1 - mx), e2 = __expf(a2 - mx), e3 = __expf(a3 - mx);
        float sum = e0 + e1 + e2 + e3;
        #pragma unroll
        for (int m = 1; m < 8; m <<= 1) sum += __shfl_xor(sum, m);
        float inv = 1.0f / sum;
        sc[i][j0] = e0 * inv; sc[i][j0 + 1] = e1 * inv; sc[i][j0 + 2] = e2 * inv; sc[i][j0 + 3] = e3 * inv;
    }
    __syncthreads();
    float o[8] = {};
    #pragma unroll
    for (int j = 0; j < 32; j++) {
        float a = sc[i][j];
        #pragma unroll
        for (int r = 0; r < 8; r++) o[r] += a * v[j][c * 8 + r];
    }
    uint4_t pk = { f2b2(o[0], o[1]), f2b2(o[2], o[3]), f2b2(o[4], o[5]), f2b2(o[6], o[7]) };
    *(uint4_t*)(OUT + (size_t)(rowbase + i) * 512 + h * 64 + c * 8) = pk;
}

// ---------------------------------------------------------------------------
// Gather strided tokens for global attention (float4 + packed cvt)
// ---------------------------------------------------------------------------
__global__ __launch_bounds__(256) void gather_xs_kernel(
    const float* __restrict__ XG, unsigned short* __restrict__ XSB)
{
    int i = blockIdx.x * 256 + threadIdx.x;   // 65536 = 262144/4
    if (i < 65536) {
        int dv = (i & 127) * 4, t = (i >> 7) & 127, b = i >> 14;
        float4_t v = *(const float4_t*)(XG + ((size_t)b * 4096 + t * 32) * 512 + dv);
        uint2_t p = { f2b2(v[0], v[1]), f2b2(v[2], v[3]) };
        *(uint2_t*)(XSB + (size_t)i * 4) = p;
    }
}

// ---------------------------------------------------------------------------
// Global attention on 128 tokens/batch. Block per (b, h, qtile of 32).
// ---------------------------------------------------------------------------
__global__ __launch_bounds__(256) void global_attn_kernel(
    const unsigned short* __restrict__ GQKV, unsigned short* __restrict__ GOUT)
{
    const int blk = blockIdx.x;       // b*32 + h*4 + qt
    const int qt = blk & 3, h = (blk >> 2) & 7, b = blk >> 5;
    __shared__ unsigned short ks[128 * 64], vs[128 * 64];
    __shared__ float qs[32 * 64];
    __shared__ float sc[32 * 128];
    const int tid = threadIdx.x;
    for (int idx = tid; idx < 128 * 64; idx += 256) {
        int j = idx >> 6, d = idx & 63;
        const unsigned short* rowp = GQKV + (size_t)(b * 128 + j) * 1536 + h * 64 + d;
        ks[idx] = rowp[512];
        vs[idx] = rowp[1024];
    }
    for (int idx = tid; idx < 32 * 64; idx += 256) {
        int i = idx >> 6, d = idx & 63;
        qs[idx] = b2f(GQKV[(size_t)(b * 128 + qt * 32 + i) * 1536 + h * 64 + d]);
    }
    __syncthreads();
    for (int idx = tid; idx < 32 * 128; idx += 256) {
        int i = idx >> 7, j = idx & 127;
        float s = 0.f;
        #pragma unroll
        for (int d = 0; d < 64; d++) s += qs[i * 64 + d] * b2f(ks[j * 64 + d]);
        sc[idx] = s * 0.125f;
    }
    __syncthreads();
    if (tid < 32) {
        float mx = -1e30f;
        for (int j = 0; j < 128; j++) mx = fmaxf(mx, sc[tid * 128 + j]);
        float sum = 0.f;
        for (int j = 0; j < 128; j++) { float e = __expf(sc[tid * 128 + j] - mx); sc[tid * 128 + j] = e; sum += e; }
        float inv = 1.0f / sum;
        for (int j = 0; j < 128; j++) sc[tid * 128 + j] *= inv;
    }
    __syncthreads();
    for (int idx = tid; idx < 32 * 64; idx += 256) {
        int i = idx >> 6, d = idx & 63;
        float o = 0.f;
        for (int j = 0; j < 128; j++) o += sc[i * 128 + j] * b2f(vs[j * 64 + d]);
        GOUT[(size_t)(b * 128 + qt * 32 + i) * 512 + h * 64 + d] = f2b(o);
    }
}

// ---------------------------------------------------------------------------
// Y = X + dwconv(X): sliding-window register version.
// ---------------------------------------------------------------------------
__global__ __launch_bounds__(256) void dwconv_add_kernel(
    const float* __restrict__ X, const float* __restrict__ wconv, const float* __restrict__ bconv,
    float* __restrict__ Yf, unsigned short* __restrict__ Yb)
{
    __shared__ float wT[7][512];
    const int tid = threadIdx.x;
    for (int idx = tid; idx < 3584; idx += 256) {
        int d = idx / 7, t = idx - d * 7;       // wconv[d*7+t] -> wT[t][d]
        wT[t][d] = wconv[idx];
    }
    __syncthreads();
    const int b = blockIdx.y;
    const int s0 = blockIdx.x * 16 + (tid >> 7) * 8;   // first output s
    const int dv = (tid & 127) * 4;
    const float* Xb = X + ((size_t)b * 4096) * 512 + dv;

    float4_t win[14];
    #pragma unroll
    for (int j = 0; j < 14; j++) {
        int ss = s0 - 3 + j;
        win[j] = (ss >= 0 && ss < 4096) ? *(const float4_t*)(Xb + (size_t)ss * 512)
                                        : (float4_t){0.f, 0.f, 0.f, 0.f};
    }
    float4_t bias = *(const float4_t*)(bconv + dv);
    float4_t w[7];
    #pragma unroll
    for (int t = 0; t < 7; t++) w[t] = *(const float4_t*)(&wT[t][dv]);

    #pragma unroll
    for (int j = 0; j < 8; j++) {
        float4_t acc = bias;
        #pragma unroll
        for (int t = 0; t < 7; t++) acc += win[j + t] * w[t];
        float4_t v = win[j + 3] + acc;          // residual from window center
        size_t e = ((size_t)b * 4096 + s0 + j) * 512 + dv;
        *(float4_t*)(Yf + e) = v;
        uint2_t o = { f2b2(v[0], v[1]), f2b2(v[2], v[3]) };
        *(uint2_t*)(Yb + e) = o;
    }
}

// ---------------------------------------------------------------------------
// out = LN(w0*XL + w1*XG), softmaxed scalar weights. Wave per row.
// ---------------------------------------------------------------------------
__global__ __launch_bounds__(256) void final_kernel(
    const float* __restrict__ XL, const float* __restrict__ XG,
    const float* __restrict__ fwl, const float* __restrict__ fwg,
    const float* __restrict__ g, const float* __restrict__ bb, float* __restrict__ out)
{
    const int row = blockIdx.x * 4 + (threadIdx.x >> 6);
    const int lane = threadIdx.x & 63;
    float a = fwl[0], cc = fwg[0];
    float m = fmaxf(a, cc);
    float ea = __expf(a - m), ec = __expf(cc - m);
    float w0 = ea / (ea + ec), w1 = ec / (ea + ec);
    const float* xlr = XL + (size_t)row * 512 + lane * 8;
    const float* xgr = XG + (size_t)row * 512 + lane * 8;
    float4_t v0 = *(const float4_t*)(xlr)     * w0 + *(const float4_t*)(xgr)     * w1;
    float4_t v1 = *(const float4_t*)(xlr + 4) * w0 + *(const float4_t*)(xgr + 4) * w1;
    float s = v0[0] + v0[1] + v0[2] + v0[3] + v1[0] + v1[1] + v1[2] + v1[3];
    #pragma unroll
    for (int mm = 32; mm > 0; mm >>= 1) s += __shfl_xor(s, mm);
    float mu = s * (1.0f / 512.0f);
    float4_t d0 = v0 - mu, d1 = v1 - mu;
    float s2 = d0[0]*d0[0] + d0[1]*d0[1] + d0[2]*d0[2] + d0[3]*d0[3]
             + d1[0]*d1[0] + d1[1]*d1[1] + d1[2]*d1[2] + d1[3]*d1[3];
    #pragma unroll
    for (int mm = 32; mm > 0; mm >>= 1) s2 += __shfl_xor(s2, mm);
    float rs = rsqrtf(s2 * (1.0f / 512.0f) + 1e-5f);
    float4_t g0 = *(const float4_t*)(g + lane * 8);
    float4_t g1 = *(const float4_t*)(g + lane * 8 + 4);
    float4_t b0 = *(const float4_t*)(bb + lane * 8);
    float4_t b1 = *(const float4_t*)(bb + lane * 8 + 4);
    float* orow = out + (size_t)row * 512 + lane * 8;
    *(float4_t*)(orow)     = d0 * rs * g0 + b0;
    *(float4_t*)(orow + 4) = d1 * rs * g1 + b1;
}

// ---------------------------------------------------------------------------
extern "C" void kernel_launch(void* const* d_in, const int* in_sizes, int n_in,
                              void* d_out, int out_size, void* d_ws, size_t ws_size,
                              hipStream_t stream)
{
    (void)in_sizes; (void)n_in; (void)out_size; (void)ws_size;
    const float* x       = (const float*)d_in[0];
    const float* lqkv_w  = (const float*)d_in[1];
    const float* lqkv_b  = (const float*)d_in[2];
    const float* lproj_w = (const float*)d_in[3];
    const float* lproj_b = (const float*)d_in[4];
    const float* lrel    = (const float*)d_in[5];
    const float* lconv_w = (const float*)d_in[6];
    const float* lconv_b = (const float*)d_in[7];
    const float* ln1_g   = (const float*)d_in[8];
    const float* ln1_b   = (const float*)d_in[9];
    const float* lffn_w1 = (const float*)d_in[10];
    const float* lffn_b1 = (const float*)d_in[11];
    const float* lffn_w2 = (const float*)d_in[12];
    const float* lffn_b2 = (const float*)d_in[13];
    const float* ln2_g   = (const float*)d_in[14];
    const float* ln2_b   = (const float*)d_in[15];
    const float* gqkv_w  = (const float*)d_in[16];
    const float* gqkv_b  = (const float*)d_in[17];
    const float* gproj_w = (const float*)d_in[18];
    const float* gproj_b = (const float*)d_in[19];
    const float* gn1_g   = (const float*)d_in[20];
    const float* gn1_b   = (const float*)d_in[21];
    const float* gffn_w1 = (const float*)d_in[22];
    const float* gffn_b1 = (const float*)d_in[23];
    const float* gffn_w2 = (const float*)d_in[24];
    const float* gffn_b2 = (const float*)d_in[25];
    const float* gn2_g   = (const float*)d_in[26];
    const float* gn2_b   = (const float*)d_in[27];
    const float* fw_local  = (const float*)d_in[28];
    const float* fw_global = (const float*)d_in[29];
    const float* fn_g    = (const float*)d_in[30];
    const float* fn_b    = (const float*)d_in[31];
    float* out = (float*)d_out;

    const int Btot = 4 * 4096;     // 16384 token rows
    const int nel = Btot * 512;    // 8388608

    char* wsb = (char*)d_ws;
    size_t off = 0;
    auto alloc = [&](size_t bytes) -> void* {
        void* p = wsb + off;
        off = (off + bytes + 255) & ~(size_t)255;
        return p;
    };
    float*          XL   = (float*)alloc((size_t)nel * 4);
    float*          XG   = (float*)alloc((size_t)nel * 4);
    float*          TMP  = (float*)alloc((size_t)nel * 4);
    unsigned short* XBl  = (unsigned short*)alloc((size_t)nel * 2);
    unsigned short* XBg  = (unsigned short*)alloc((size_t)nel * 2);
    unsigned short* AOUT = (unsigned short*)alloc((size_t)nel * 2);
    unsigned short* BIG  = (unsigned short*)alloc((size_t)Btot * 2048 * 2);
    unsigned short* WT   = (unsigned short*)alloc((size_t)22020096 * 2);
    unsigned short* XSB  = (unsigned short*)alloc((size_t)512 * 512 * 2);
    unsigned short* GQKV = (unsigned short*)alloc((size_t)512 * 1536 * 2);
    unsigned short* GOUT = (unsigned short*)alloc((size_t)512 * 512 * 2);
    float*          GA   = (float*)alloc((size_t)512 * 512 * 4);

    const size_t perL = 3145728;   // bf16 elems of transposed weights per layer
    {
        dim3 blk(256);
        transpose_cast_batch_kernel<<<dim3(1536/32, 512/32, 7), blk, 0, stream>>>(
            lqkv_w, gqkv_w, 4, WT, perL, 512, 1536);
        transpose_cast_batch_kernel<<<dim3(512/32, 512/32, 7), blk, 0, stream>>>(
            lproj_w, gproj_w, 4, WT + 786432, perL, 512, 512);
        transpose_cast_batch_kernel<<<dim3(2048/32, 512/32, 7), blk, 0, stream>>>(
            lffn_w1, gffn_w1, 4, WT + 786432 + 262144, perL, 512, 2048);
        transpose_cast_batch_kernel<<<dim3(512/32, 2048/32, 7), blk, 0, stream>>>(
            lffn_w2, gffn_w2, 4, WT + 786432 + 262144 + 1048576, perL, 2048, 512);
    }

    copy_cast_kernel<<<dim3(nel / 1024), dim3(256), 0, stream>>>(x, XL, XG, XBl, nel / 4);

    auto gemm = [&](const unsigned short* A_, const unsigned short* BT_, const float* bias_,
                    const float* res_, float* Cf_, unsigned short* Cb_,
                    int M_, int N_, int K_, int act_) {
        if (N_ >= 1024 || M_ >= 1024) {
            dim3 g(M_ / 128, N_ / 128);
            gemm_rp_kernel<128><<<g, dim3(256), 0, stream>>>(A_, BT_, bias_, res_, Cf_, Cb_, M_, N_, K_, act_);
        } else {
            dim3 g(M_ / 128, N_ / 64);
            gemm_rp_kernel<64><<<g, dim3(256), 0, stream>>>(A_, BT_, bias_, res_, Cf_, Cb_, M_, N_, K_, act_);
        }
    };

    // ---------------- local branch: 4 layers ----------------
    for (int i = 0; i < 4; i++) {
        unsigned short* base  = WT + (size_t)i * perL;
        unsigned short* qkvT  = base;
        unsigned short* projT = base + 786432;
        unsigned short* w1T   = base + 786432 + 262144;
        unsigned short* w2T   = base + 786432 + 262144 + 1048576;

        gemm(XBl, qkvT, lqkv_b + i * 1536, nullptr, nullptr, BIG, Btot, 1536, 512, 0);
        local_attn_kernel<<<dim3(4096), dim3(256), 0, stream>>>(BIG, lrel + (size_t)i * 63 * 8, AOUT);
        gemm(AOUT, projT, lproj_b + i * 512, XL, TMP, nullptr, Btot, 512, 512, 0);
        ln_kernel<<<dim3(Btot / 4), dim3(256), 0, stream>>>(TMP, ln1_g + i * 512, ln1_b + i * 512, XL, (unsigned short*)nullptr);
        dwconv_add_kernel<<<dim3(256, 4), dim3(256), 0, stream>>>(XL, lconv_w + (size_t)i * 512 * 7, lconv_b + i * 512, TMP, XBl);
        gemm(XBl, w1T, lffn_b1 + i * 2048, nullptr, nullptr, BIG, Btot, 2048, 512, 1);
        gemm(BIG, w2T, lffn_b2 + i * 512, TMP, TMP, nullptr, Btot, 512, 2048, 0);
        ln_kernel<<<dim3(Btot / 4), dim3(256), 0, stream>>>(TMP, ln2_g + i * 512, ln2_b + i * 512, XL, XBl);
    }

    // ---------------- global branch: 3 layers ----------------
    for (int i = 0; i < 3; i++) {
        unsigned short* base  = WT + (size_t)(4 + i) * perL;
        unsigned short* qkvT  = base;
        unsigned short* projT = base + 786432;
        unsigned short* w1T   = base + 786432 + 262144;
        unsigned short* w2T   = base + 786432 + 262144 + 1048576;

        gather_xs_kernel<<<dim3(256), dim3(256), 0, stream>>>(XG, XSB);
        gemm(XSB, qkvT, gqkv_b + i * 1536, nullptr, nullptr, GQKV, 512, 1536, 512, 0);
        global_attn_kernel<<<dim3(128), dim3(256), 0, stream>>>(GQKV, GOUT);
        gemm(GOUT, projT, gproj_b + i * 512, nullptr, GA, nullptr, 512, 512, 512, 0);
        interp_ln_kernel<<<dim3(Btot / 4), dim3(256), 0, stream>>>(GA, XG, gn1_g + i * 512, gn1_b + i * 512, XBg);
        gemm(XBg, w1T, gffn_b1 + i * 2048, nullptr, nullptr, BIG, Btot, 2048, 512, 1);
        gemm(BIG, w2T, gffn_b2 + i * 512, XG, TMP, nullptr, Btot, 512, 2048, 0);
        ln_kernel<<<dim3(Btot / 4), dim3(256), 0, stream>>>(TMP, gn2_g + i * 512, gn2_b + i * 512, XG, XBg);
    }

    final_kernel<<<dim3(Btot / 4), dim3(256), 0, stream>>>(XL, XG, fw_local, fw_global, fn_g, fn_b, out);
}

// Round 11
// 1816.958 us; speedup vs baseline: 1.2549x; 1.0101x over previous
//
#include <hip/hip_runtime.h>
#include <hip/hip_bf16.h>
#include <math.h>

typedef __attribute__((ext_vector_type(8))) short short8;
typedef __attribute__((ext_vector_type(4))) float float4_t;
typedef __attribute__((ext_vector_type(4))) unsigned int uint4_t;
typedef __attribute__((ext_vector_type(2))) unsigned int uint2_t;

#define DEV static __device__ __forceinline__

DEV unsigned short f2b(float f) {
    union { float f; unsigned int u; } x; x.f = f;
    unsigned int r = x.u + 0x7fffu + ((x.u >> 16) & 1u);
    return (unsigned short)(r >> 16);
}
DEV float b2f(unsigned short u) {
    union { unsigned int u; float f; } x; x.u = ((unsigned int)u) << 16;
    return x.f;
}
// packed 2x f32 -> 2x bf16 (v_cvt_pk_bf16_f32 on gfx950, RNE)
DEV unsigned int f2b2(float lo, float hi) {
    union { __hip_bfloat162 h; unsigned int u; } c;
    c.h = __float22bfloat162_rn(make_float2(lo, hi));
    return c.u;
}
// gelu(x) = x / (1 + 2^(a*x + b*x^3));  a = -2*0.7978845608*log2(e)
DEV float gelu_f(float x) {
    const float a = -2.3022082f, b = -0.10294372f;
    float x2 = x * x;
    float p = __builtin_fmaf(x2, b, a);          // a + b*x^2
    float e = __builtin_amdgcn_exp2f(p * x);     // 2^(a x + b x^3)
    return x * __builtin_amdgcn_rcpf(1.0f + e);
}

// ---------------------------------------------------------------------------
// Batched tiled transpose + cast: W[z] (K x N, f32) -> WT[z] (N x K, bf16)
// ---------------------------------------------------------------------------
__global__ __launch_bounds__(256) void transpose_cast_batch_kernel(
    const float* __restrict__ srcL, const float* __restrict__ srcG, int nl,
    unsigned short* __restrict__ dst0, size_t perL, int Kd, int Nd)
{
    const int z = blockIdx.z;
    const float* W = (z < nl) ? srcL + (size_t)z * Kd * Nd
                              : srcG + (size_t)(z - nl) * Kd * Nd;
    unsigned short* WT = dst0 + (size_t)z * perL;
    __shared__ float tile[32][33];
    int n0 = blockIdx.x * 32, k0 = blockIdx.y * 32;
    int tx = threadIdx.x & 31, ty = threadIdx.x >> 5;   // 32 x 8
    #pragma unroll
    for (int r = ty; r < 32; r += 8)
        tile[r][tx] = W[(size_t)(k0 + r) * Nd + n0 + tx];
    __syncthreads();
    #pragma unroll
    for (int r = ty; r < 32; r += 8)
        WT[(size_t)(n0 + r) * Kd + k0 + tx] = f2b(tile[tx][r]);
}

// ---------------------------------------------------------------------------
// copy x -> XL (f32), XG (f32), XB (bf16), float4-vectorized
// ---------------------------------------------------------------------------
__global__ __launch_bounds__(256) void copy_cast_kernel(
    const float* __restrict__ x, float* __restrict__ xl, float* __restrict__ xg,
    unsigned short* __restrict__ xb, int n4)
{
    int i = blockIdx.x * 256 + threadIdx.x;
    if (i < n4) {
        float4_t v = ((const float4_t*)x)[i];
        ((float4_t*)xl)[i] = v;
        ((float4_t*)xg)[i] = v;
        uint2_t p = { f2b2(v[0], v[1]), f2b2(v[2], v[3]) };
        ((uint2_t*)xb)[i] = p;
    }
}

// ---------------------------------------------------------------------------
// bf16 MFMA GEMM — register-staged pipeline (round-8 structure, best known:
// 1835 us total). Further GEMM structure work is exhausted: all staging
// variants pin MfmaUtil at ~21% because __syncthreads drains ALL vmem
// (verified empirically rounds 1/4/5/6/7/8); floor for this regime ~26%.
// ---------------------------------------------------------------------------
template<int BN>
__global__ __launch_bounds__(256, 4) void gemm_rp_kernel(
    const unsigned short* __restrict__ A,
    const unsigned short* __restrict__ BT,
    const float* __restrict__ bias,
    const float* __restrict__ residual,
    float* __restrict__ Cf,
    unsigned short* __restrict__ Cb,
    int M, int N, int K, int act)
{
    constexpr int NI = (BN == 128) ? 4 : 2;
    __shared__ __align__(16) unsigned short As[2][128 * 32];
    __shared__ __align__(16) unsigned short Bs[2][BN * 32];
    const int tid = threadIdx.x;
    const int wave = tid >> 6, lane = tid & 63;
    const int quad = lane >> 4, l16 = lane & 15;
    const int m0 = blockIdx.x * 128, n0 = blockIdx.y * BN;
    const int wm = (BN == 128) ? (wave >> 1) * 64 : wave * 32;
    const int wn = (BN == 128) ? (wave & 1) * 64 : 0;

    float4_t acc[NI][4] = {};

    const int lrow = lane >> 2;
    const int lcol = (lane & 3) * 8;
    const int r0 = wave * 16 + lrow;
    const unsigned short* Ag0 = A  + (size_t)(m0 + r0) * K + lcol;
    const unsigned short* Ag1 = A  + (size_t)(m0 + 64 + r0) * K + lcol;
    const unsigned short* Bg0 = BT + (size_t)(n0 + r0) * K + lcol;
    const unsigned short* Bg1 = (BN == 128) ? BT + (size_t)(n0 + 64 + r0) * K + lcol : nullptr;
    const int soff = (wave * 16) * 32 + lane * 8;

    const int iters = K >> 5;

    uint4_t rA0, rA1, rB0, rB1;
    rA0 = *(const uint4_t*)(Ag0);
    rA1 = *(const uint4_t*)(Ag1);
    rB0 = *(const uint4_t*)(Bg0);
    if (BN == 128) rB1 = *(const uint4_t*)(Bg1);
    *(uint4_t*)(&As[0][soff])           = rA0;
    *(uint4_t*)(&As[0][soff + 64 * 32]) = rA1;
    *(uint4_t*)(&Bs[0][soff])           = rB0;
    if (BN == 128) *(uint4_t*)(&Bs[0][soff + 64 * 32]) = rB1;
    if (iters > 1) {
        rA0 = *(const uint4_t*)(Ag0 + 32);
        rA1 = *(const uint4_t*)(Ag1 + 32);
        rB0 = *(const uint4_t*)(Bg0 + 32);
        if (BN == 128) rB1 = *(const uint4_t*)(Bg1 + 32);
    }
    __syncthreads();

    for (int k = 0; k < iters; k++) {
        const int cur = k & 1;
        if (k + 1 < iters) {
            const int nxt = cur ^ 1;
            *(uint4_t*)(&As[nxt][soff])           = rA0;
            *(uint4_t*)(&As[nxt][soff + 64 * 32]) = rA1;
            *(uint4_t*)(&Bs[nxt][soff])           = rB0;
            if (BN == 128) *(uint4_t*)(&Bs[nxt][soff + 64 * 32]) = rB1;
            if (k + 2 < iters) {
                const int koff = (k + 2) << 5;
                rA0 = *(const uint4_t*)(Ag0 + koff);
                rA1 = *(const uint4_t*)(Ag1 + koff);
                rB0 = *(const uint4_t*)(Bg0 + koff);
                if (BN == 128) rB1 = *(const uint4_t*)(Bg1 + koff);
            }
        }
        short8 a[NI], b[4];
        #pragma unroll
        for (int i = 0; i < NI; i++)
            a[i] = *(const short8*)(&As[cur][(wm + i * 16 + l16) * 32 + quad * 8]);
        #pragma unroll
        for (int j = 0; j < 4; j++)
            b[j] = *(const short8*)(&Bs[cur][(wn + j * 16 + l16) * 32 + quad * 8]);
        #pragma unroll
        for (int i = 0; i < NI; i++)
            #pragma unroll
            for (int j = 0; j < 4; j++)
                acc[i][j] = __builtin_amdgcn_mfma_f32_16x16x32_bf16(b[j], a[i], acc[i][j], 0, 0, 0);
        __syncthreads();
    }

    #pragma unroll
    for (int i = 0; i < NI; i++) {
        const int row = m0 + wm + i * 16 + l16;
        #pragma unroll
        for (int j = 0; j < 4; j++) {
            const int col = n0 + wn + j * 16 + quad * 4;
            const size_t idx = (size_t)row * N + col;
            float4_t v = acc[i][j] + *(const float4_t*)(bias + col);
            if (act == 1) {
                #pragma unroll
                for (int r2 = 0; r2 < 4; r2++) v[r2] = gelu_f(v[r2]);
            }
            if (residual) v += *(const float4_t*)(residual + idx);
            if (Cf) *(float4_t*)(Cf + idx) = v;
            if (Cb) {
                uint2_t o = { f2b2(v[0], v[1]), f2b2(v[2], v[3]) };
                *(uint2_t*)(Cb + idx) = o;
            }
        }
    }
}

// ---------------------------------------------------------------------------
// LayerNorm over D=512, one WAVE per row (no barriers). 4 rows/block.
// ---------------------------------------------------------------------------
__global__ __launch_bounds__(256) void ln_kernel(
    const float* __restrict__ X, const float* __restrict__ g, const float* __restrict__ b,
    float* __restrict__ Yf, unsigned short* __restrict__ Yb)
{
    const int row = blockIdx.x * 4 + (threadIdx.x >> 6);
    const int lane = threadIdx.x & 63;
    const float* xr = X + (size_t)row * 512 + lane * 8;
    float4_t v0 = *(const float4_t*)(xr);
    float4_t v1 = *(const float4_t*)(xr + 4);
    float s = v0[0] + v0[1] + v0[2] + v0[3] + v1[0] + v1[1] + v1[2] + v1[3];
    #pragma unroll
    for (int m = 32; m > 0; m >>= 1) s += __shfl_xor(s, m);
    float mu = s * (1.0f / 512.0f);
    float4_t d0 = v0 - mu, d1 = v1 - mu;
    float s2 = d0[0]*d0[0] + d0[1]*d0[1] + d0[2]*d0[2] + d0[3]*d0[3]
             + d1[0]*d1[0] + d1[1]*d1[1] + d1[2]*d1[2] + d1[3]*d1[3];
    #pragma unroll
    for (int m = 32; m > 0; m >>= 1) s2 += __shfl_xor(s2, m);
    float rs = rsqrtf(s2 * (1.0f / 512.0f) + 1e-5f);
    float4_t g0 = *(const float4_t*)(g + lane * 8);
    float4_t g1 = *(const float4_t*)(g + lane * 8 + 4);
    float4_t b0 = *(const float4_t*)(b + lane * 8);
    float4_t b1 = *(const float4_t*)(b + lane * 8 + 4);
    float4_t y0 = d0 * rs * g0 + b0;
    float4_t y1 = d1 * rs * g1 + b1;
    if (Yf) {
        float* yr = Yf + (size_t)row * 512 + lane * 8;
        *(float4_t*)(yr) = y0;
        *(float4_t*)(yr + 4) = y1;
    }
    if (Yb) {
        uint4_t pk = { f2b2(y0[0], y0[1]), f2b2(y0[2], y0[3]),
                       f2b2(y1[0], y1[1]), f2b2(y1[2], y1[3]) };
        *(uint4_t*)(Yb + (size_t)row * 512 + lane * 8) = pk;
    }
}

// ---------------------------------------------------------------------------
// Fused: v = XG + lin_interp(GA 128->4096); XG = LN(v); XBg = bf16. Wave/row.
// ---------------------------------------------------------------------------
__global__ __launch_bounds__(256) void interp_ln_kernel(
    const float* __restrict__ GA, float* __restrict__ XG,
    const float* __restrict__ g, const float* __restrict__ b,
    unsigned short* __restrict__ Yb)
{
    const int row = blockIdx.x * 4 + (threadIdx.x >> 6);
    const int lane = threadIdx.x & 63;
    const int bb = row >> 12, sfull = row & 4095;
    float pos = (sfull + 0.5f) * (128.0f / 4096.0f) - 0.5f;
    pos = fminf(fmaxf(pos, 0.0f), 127.0f);
    int i0 = (int)floorf(pos);
    int i1 = min(i0 + 1, 127);
    float w = pos - (float)i0;
    const float* ga0 = GA + ((size_t)bb * 128 + i0) * 512 + lane * 8;
    const float* ga1 = GA + ((size_t)bb * 128 + i1) * 512 + lane * 8;
    float* xr = XG + (size_t)row * 512 + lane * 8;
    float4_t v0 = *(const float4_t*)(xr)     + *(const float4_t*)(ga0)     * (1.0f - w) + *(const float4_t*)(ga1)     * w;
    float4_t v1 = *(const float4_t*)(xr + 4) + *(const float4_t*)(ga0 + 4) * (1.0f - w) + *(const float4_t*)(ga1 + 4) * w;
    float s = v0[0] + v0[1] + v0[2] + v0[3] + v1[0] + v1[1] + v1[2] + v1[3];
    #pragma unroll
    for (int m = 32; m > 0; m >>= 1) s += __shfl_xor(s, m);
    float mu = s * (1.0f / 512.0f);
    float4_t d0 = v0 - mu, d1 = v1 - mu;
    float s2 = d0[0]*d0[0] + d0[1]*d0[1] + d0[2]*d0[2] + d0[3]*d0[3]
             + d1[0]*d1[0] + d1[1]*d1[1] + d1[2]*d1[2] + d1[3]*d1[3];
    #pragma unroll
    for (int m = 32; m > 0; m >>= 1) s2 += __shfl_xor(s2, m);
    float rs = rsqrtf(s2 * (1.0f / 512.0f) + 1e-5f);
    float4_t g0 = *(const float4_t*)(g + lane * 8);
    float4_t g1 = *(const float4_t*)(g + lane * 8 + 4);
    float4_t b0 = *(const float4_t*)(b + lane * 8);
    float4_t b1 = *(const float4_t*)(b + lane * 8 + 4);
    float4_t y0 = d0 * rs * g0 + b0;
    float4_t y1 = d1 * rs * g1 + b1;
    *(float4_t*)(xr) = y0;
    *(float4_t*)(xr + 4) = y1;
    uint4_t pk = { f2b2(y0[0], y0[1]), f2b2(y0[2], y0[3]),
                   f2b2(y1[0], y1[1]), f2b2(y1[2], y1[3]) };
    *(uint4_t*)(Yb + (size_t)row * 512 + lane * 8) = pk;
}

// ---------------------------------------------------------------------------
// Local windowed attention — round-8 proven scalar structure (the MFMA
// rewrite failed the container twice in rounds 9/10 and is abandoned),
// with LDS traffic vectorized:
//  * k padded to [32][68] (row stride 272B = 17x16B) -> float4-aligned rows;
//    QK^T inner loop uses ds_read_b128 (16 vec reads vs 64 scalar per side;
//    ~4-way bank conflicts cost 1.58x but 4x fewer issues -> net ~2.5x).
//  * PV loop reads v via 2x float4 per j (rows are 256B, aligned).
// Everything else identical to the round-8 passing kernel.
// ---------------------------------------------------------------------------
__global__ __launch_bounds__(256) void local_attn_kernel(
    const unsigned short* __restrict__ QKV, const float* __restrict__ rel,
    unsigned short* __restrict__ OUT)
{
    const int blk = blockIdx.x;          // (b*128 + win)*8 + h
    const int h = blk & 7;
    const int win = (blk >> 3) & 127;
    const int b = blk >> 10;
    const int rowbase = b * 4096 + win * 32;
    __shared__ __align__(16) float q[32][64];
    __shared__ __align__(16) float k[32][68];
    __shared__ __align__(16) float v[32][64];
    __shared__ float sc[32][33];
    const int tid = threadIdx.x;
    const int i = tid >> 3, c = tid & 7;     // row 0..31, chunk 0..7
    {
        const unsigned short* base = QKV + (size_t)(rowbase + i) * 1536 + h * 64 + c * 8;
        short8 qv = *(const short8*)(base);
        short8 kv = *(const short8*)(base + 512);
        short8 vv = *(const short8*)(base + 1024);
        #pragma unroll
        for (int r = 0; r < 8; r++) {
            q[i][c * 8 + r] = b2f((unsigned short)qv[r]);
            k[i][c * 8 + r] = b2f((unsigned short)kv[r]);
            v[i][c * 8 + r] = b2f((unsigned short)vv[r]);
        }
    }
    __syncthreads();
    #pragma unroll
    for (int p = 0; p < 4; p++) {
        int idx = tid + p * 256;
        int si = idx >> 5, sj = idx & 31;
        float s = 0.f;
        #pragma unroll
        for (int d4 = 0; d4 < 16; d4++) {
            float4_t qv = *(const float4_t*)(&q[si][d4 * 4]);
            float4_t kv = *(const float4_t*)(&k[sj][d4 * 4]);
            s += qv[0] * kv[0] + qv[1] * kv[1] + qv[2] * kv[2] + qv[3] * kv[3];
        }
        sc[si][sj] = s * 0.125f + rel[(si - sj + 31) * 8 + h];
    }
    __syncthreads();
    {
        const int j0 = c * 4;
        float a0 = sc[i][j0], a1 = sc[i][j0 + 1], a2 = sc[i][j0 + 2], a3 = sc[i][j0 + 3];
        float mx = fmaxf(fmaxf(a0, a1), fmaxf(a2, a3));
        #pragma unroll
        for (int m = 1; m < 8; m <<= 1) mx = fmaxf(mx, __shfl_xor(mx, m));
        float e0 = __expf(a0 - mx), e1 = __expf(a1 - mx), e2 = __expf(a2 - mx), e3 = __expf(a3 - mx);
        float sum = e0 + e1 + e2 + e3;
        #pragma unroll
        for (int m = 1; m < 8; m <<= 1) sum += __shfl_xor(sum, m);
        float inv = 1.0f / sum;
        sc[i][j0] = e0 * inv; sc[i][j0 + 1] = e1 * inv; sc[i][j0 + 2] = e2 * inv; sc[i][j0 + 3] = e3 * inv;
    }
    __syncthreads();
    float4_t o0 = {0.f, 0.f, 0.f, 0.f}, o1 = {0.f, 0.f, 0.f, 0.f};
    #pragma unroll
    for (int j = 0; j < 32; j++) {
        float a = sc[i][j];
        float4_t va = *(const float4_t*)(&v[j][c * 8]);
        float4_t vb = *(const float4_t*)(&v[j][c * 8 + 4]);
        o0 += va * a;
        o1 += vb * a;
    }
    uint4_t pk = { f2b2(o0[0], o0[1]), f2b2(o0[2], o0[3]), f2b2(o1[0], o1[1]), f2b2(o1[2], o1[3]) };
    *(uint4_t*)(OUT + (size_t)(rowbase + i) * 512 + h * 64 + c * 8) = pk;
}

// ---------------------------------------------------------------------------
// Gather strided tokens for global attention (float4 + packed cvt)
// ---------------------------------------------------------------------------
__global__ __launch_bounds__(256) void gather_xs_kernel(
    const float* __restrict__ XG, unsigned short* __restrict__ XSB)
{
    int i = blockIdx.x * 256 + threadIdx.x;   // 65536 = 262144/4
    if (i < 65536) {
        int dv = (i & 127) * 4, t = (i >> 7) & 127, b = i >> 14;
        float4_t v = *(const float4_t*)(XG + ((size_t)b * 4096 + t * 32) * 512 + dv);
        uint2_t p = { f2b2(v[0], v[1]), f2b2(v[2], v[3]) };
        *(uint2_t*)(XSB + (size_t)i * 4) = p;
    }
}

// ---------------------------------------------------------------------------
// Global attention on 128 tokens/batch. Block per (b, h, qtile of 32).
// ---------------------------------------------------------------------------
__global__ __launch_bounds__(256) void global_attn_kernel(
    const unsigned short* __restrict__ GQKV, unsigned short* __restrict__ GOUT)
{
    const int blk = blockIdx.x;       // b*32 + h*4 + qt
    const int qt = blk & 3, h = (blk >> 2) & 7, b = blk >> 5;
    __shared__ unsigned short ks[128 * 64], vs[128 * 64];
    __shared__ float qs[32 * 64];
    __shared__ float sc[32 * 128];
    const int tid = threadIdx.x;
    for (int idx = tid; idx < 128 * 64; idx += 256) {
        int j = idx >> 6, d = idx & 63;
        const unsigned short* rowp = GQKV + (size_t)(b * 128 + j) * 1536 + h * 64 + d;
        ks[idx] = rowp[512];
        vs[idx] = rowp[1024];
    }
    for (int idx = tid; idx < 32 * 64; idx += 256) {
        int i = idx >> 6, d = idx & 63;
        qs[idx] = b2f(GQKV[(size_t)(b * 128 + qt * 32 + i) * 1536 + h * 64 + d]);
    }
    __syncthreads();
    for (int idx = tid; idx < 32 * 128; idx += 256) {
        int i = idx >> 7, j = idx & 127;
        float s = 0.f;
        #pragma unroll
        for (int d = 0; d < 64; d++) s += qs[i * 64 + d] * b2f(ks[j * 64 + d]);
        sc[idx] = s * 0.125f;
    }
    __syncthreads();
    if (tid < 32) {
        float mx = -1e30f;
        for (int j = 0; j < 128; j++) mx = fmaxf(mx, sc[tid * 128 + j]);
        float sum = 0.f;
        for (int j = 0; j < 128; j++) { float e = __expf(sc[tid * 128 + j] - mx); sc[tid * 128 + j] = e; sum += e; }
        float inv = 1.0f / sum;
        for (int j = 0; j < 128; j++) sc[tid * 128 + j] *= inv;
    }
    __syncthreads();
    for (int idx = tid; idx < 32 * 64; idx += 256) {
        int i = idx >> 6, d = idx & 63;
        float o = 0.f;
        for (int j = 0; j < 128; j++) o += sc[i * 128 + j] * b2f(vs[j * 64 + d]);
        GOUT[(size_t)(b * 128 + qt * 32 + i) * 512 + h * 64 + d] = f2b(o);
    }
}

// ---------------------------------------------------------------------------
// Y = X + dwconv(X): sliding-window register version.
// ---------------------------------------------------------------------------
__global__ __launch_bounds__(256) void dwconv_add_kernel(
    const float* __restrict__ X, const float* __restrict__ wconv, const float* __restrict__ bconv,
    float* __restrict__ Yf, unsigned short* __restrict__ Yb)
{
    __shared__ float wT[7][512];
    const int tid = threadIdx.x;
    for (int idx = tid; idx < 3584; idx += 256) {
        int d = idx / 7, t = idx - d * 7;       // wconv[d*7+t] -> wT[t][d]
        wT[t][d] = wconv[idx];
    }
    __syncthreads();
    const int b = blockIdx.y;
    const int s0 = blockIdx.x * 16 + (tid >> 7) * 8;   // first output s
    const int dv = (tid & 127) * 4;
    const float* Xb = X + ((size_t)b * 4096) * 512 + dv;

    float4_t win[14];
    #pragma unroll
    for (int j = 0; j < 14; j++) {
        int ss = s0 - 3 + j;
        win[j] = (ss >= 0 && ss < 4096) ? *(const float4_t*)(Xb + (size_t)ss * 512)
                                        : (float4_t){0.f, 0.f, 0.f, 0.f};
    }
    float4_t bias = *(const float4_t*)(bconv + dv);
    float4_t w[7];
    #pragma unroll
    for (int t = 0; t < 7; t++) w[t] = *(const float4_t*)(&wT[t][dv]);

    #pragma unroll
    for (int j = 0; j < 8; j++) {
        float4_t acc = bias;
        #pragma unroll
        for (int t = 0; t < 7; t++) acc += win[j + t] * w[t];
        float4_t v = win[j + 3] + acc;          // residual from window center
        size_t e = ((size_t)b * 4096 + s0 + j) * 512 + dv;
        *(float4_t*)(Yf + e) = v;
        uint2_t o = { f2b2(v[0], v[1]), f2b2(v[2], v[3]) };
        *(uint2_t*)(Yb + e) = o;
    }
}

// ---------------------------------------------------------------------------
// out = LN(w0*XL + w1*XG), softmaxed scalar weights. Wave per row.
// ---------------------------------------------------------------------------
__global__ __launch_bounds__(256) void final_kernel(
    const float* __restrict__ XL, const float* __restrict__ XG,
    const float* __restrict__ fwl, const float* __restrict__ fwg,
    const float* __restrict__ g, const float* __restrict__ bb, float* __restrict__ out)
{
    const int row = blockIdx.x * 4 + (threadIdx.x >> 6);
    const int lane = threadIdx.x & 63;
    float a = fwl[0], cc = fwg[0];
    float m = fmaxf(a, cc);
    float ea = __expf(a - m), ec = __expf(cc - m);
    float w0 = ea / (ea + ec), w1 = ec / (ea + ec);
    const float* xlr = XL + (size_t)row * 512 + lane * 8;
    const float* xgr = XG + (size_t)row * 512 + lane * 8;
    float4_t v0 = *(const float4_t*)(xlr)     * w0 + *(const float4_t*)(xgr)     * w1;
    float4_t v1 = *(const float4_t*)(xlr + 4) * w0 + *(const float4_t*)(xgr + 4) * w1;
    float s = v0[0] + v0[1] + v0[2] + v0[3] + v1[0] + v1[1] + v1[2] + v1[3];
    #pragma unroll
    for (int mm = 32; mm > 0; mm >>= 1) s += __shfl_xor(s, mm);
    float mu = s * (1.0f / 512.0f);
    float4_t d0 = v0 - mu, d1 = v1 - mu;
    float s2 = d0[0]*d0[0] + d0[1]*d0[1] + d0[2]*d0[2] + d0[3]*d0[3]
             + d1[0]*d1[0] + d1[1]*d1[1] + d1[2]*d1[2] + d1[3]*d1[3];
    #pragma unroll
    for (int mm = 32; mm > 0; mm >>= 1) s2 += __shfl_xor(s2, mm);
    float rs = rsqrtf(s2 * (1.0f / 512.0f) + 1e-5f);
    float4_t g0 = *(const float4_t*)(g + lane * 8);
    float4_t g1 = *(const float4_t*)(g + lane * 8 + 4);
    float4_t b0 = *(const float4_t*)(bb + lane * 8);
    float4_t b1 = *(const float4_t*)(bb + lane * 8 + 4);
    float* orow = out + (size_t)row * 512 + lane * 8;
    *(float4_t*)(orow)     = d0 * rs * g0 + b0;
    *(float4_t*)(orow + 4) = d1 * rs * g1 + b1;
}

// ---------------------------------------------------------------------------
extern "C" void kernel_launch(void* const* d_in, const int* in_sizes, int n_in,
                              void* d_out, int out_size, void* d_ws, size_t ws_size,
                              hipStream_t stream)
{
    (void)in_sizes; (void)n_in; (void)out_size; (void)ws_size;
    const float* x       = (const float*)d_in[0];
    const float* lqkv_w  = (const float*)d_in[1];
    const float* lqkv_b  = (const float*)d_in[2];
    const float* lproj_w = (const float*)d_in[3];
    const float* lproj_b = (const float*)d_in[4];
    const float* lrel    = (const float*)d_in[5];
    const float* lconv_w = (const float*)d_in[6];
    const float* lconv_b = (const float*)d_in[7];
    const float* ln1_g   = (const float*)d_in[8];
    const float* ln1_b   = (const float*)d_in[9];
    const float* lffn_w1 = (const float*)d_in[10];
    const float* lffn_b1 = (const float*)d_in[11];
    const float* lffn_w2 = (const float*)d_in[12];
    const float* lffn_b2 = (const float*)d_in[13];
    const float* ln2_g   = (const float*)d_in[14];
    const float* ln2_b   = (const float*)d_in[15];
    const float* gqkv_w  = (const float*)d_in[16];
    const float* gqkv_b  = (const float*)d_in[17];
    const float* gproj_w = (const float*)d_in[18];
    const float* gproj_b = (const float*)d_in[19];
    const float* gn1_g   = (const float*)d_in[20];
    const float* gn1_b   = (const float*)d_in[21];
    const float* gffn_w1 = (const float*)d_in[22];
    const float* gffn_b1 = (const float*)d_in[23];
    const float* gffn_w2 = (const float*)d_in[24];
    const float* gffn_b2 = (const float*)d_in[25];
    const float* gn2_g   = (const float*)d_in[26];
    const float* gn2_b   = (const float*)d_in[27];
    const float* fw_local  = (const float*)d_in[28];
    const float* fw_global = (const float*)d_in[29];
    const float* fn_g    = (const float*)d_in[30];
    const float* fn_b    = (const float*)d_in[31];
    float* out = (float*)d_out;

    const int Btot = 4 * 4096;     // 16384 token rows
    const int nel = Btot * 512;    // 8388608

    char* wsb = (char*)d_ws;
    size_t off = 0;
    auto alloc = [&](size_t bytes) -> void* {
        void* p = wsb + off;
        off = (off + bytes + 255) & ~(size_t)255;
        return p;
    };
    float*          XL   = (float*)alloc((size_t)nel * 4);
    float*          XG   = (float*)alloc((size_t)nel * 4);
    float*          TMP  = (float*)alloc((size_t)nel * 4);
    unsigned short* XBl  = (unsigned short*)alloc((size_t)nel * 2);
    unsigned short* XBg  = (unsigned short*)alloc((size_t)nel * 2);
    unsigned short* AOUT = (unsigned short*)alloc((size_t)nel * 2);
    unsigned short* BIG  = (unsigned short*)alloc((size_t)Btot * 2048 * 2);
    unsigned short* WT   = (unsigned short*)alloc((size_t)22020096 * 2);
    unsigned short* XSB  = (unsigned short*)alloc((size_t)512 * 512 * 2);
    unsigned short* GQKV = (unsigned short*)alloc((size_t)512 * 1536 * 2);
    unsigned short* GOUT = (unsigned short*)alloc((size_t)512 * 512 * 2);
    float*          GA   = (float*)alloc((size_t)512 * 512 * 4);

    const size_t perL = 3145728;   // bf16 elems of transposed weights per layer
    {
        dim3 blk(256);
        transpose_cast_batch_kernel<<<dim3(1536/32, 512/32, 7), blk, 0, stream>>>(
            lqkv_w, gqkv_w, 4, WT, perL, 512, 1536);
        transpose_cast_batch_kernel<<<dim3(512/32, 512/32, 7), blk, 0, stream>>>(
            lproj_w, gproj_w, 4, WT + 786432, perL, 512, 512);
        transpose_cast_batch_kernel<<<dim3(2048/32, 512/32, 7), blk, 0, stream>>>(
            lffn_w1, gffn_w1, 4, WT + 786432 + 262144, perL, 512, 2048);
        transpose_cast_batch_kernel<<<dim3(512/32, 2048/32, 7), blk, 0, stream>>>(
            lffn_w2, gffn_w2, 4, WT + 786432 + 262144 + 1048576, perL, 2048, 512);
    }

    copy_cast_kernel<<<dim3(nel / 1024), dim3(256), 0, stream>>>(x, XL, XG, XBl, nel / 4);

    auto gemm = [&](const unsigned short* A_, const unsigned short* BT_, const float* bias_,
                    const float* res_, float* Cf_, unsigned short* Cb_,
                    int M_, int N_, int K_, int act_) {
        if (N_ >= 1024 || M_ >= 1024) {
            dim3 g(M_ / 128, N_ / 128);
            gemm_rp_kernel<128><<<g, dim3(256), 0, stream>>>(A_, BT_, bias_, res_, Cf_, Cb_, M_, N_, K_, act_);
        } else {
            dim3 g(M_ / 128, N_ / 64);
            gemm_rp_kernel<64><<<g, dim3(256), 0, stream>>>(A_, BT_, bias_, res_, Cf_, Cb_, M_, N_, K_, act_);
        }
    };

    // ---------------- local branch: 4 layers ----------------
    for (int i = 0; i < 4; i++) {
        unsigned short* base  = WT + (size_t)i * perL;
        unsigned short* qkvT  = base;
        unsigned short* projT = base + 786432;
        unsigned short* w1T   = base + 786432 + 262144;
        unsigned short* w2T   = base + 786432 + 262144 + 1048576;

        gemm(XBl, qkvT, lqkv_b + i * 1536, nullptr, nullptr, BIG, Btot, 1536, 512, 0);
        local_attn_kernel<<<dim3(4096), dim3(256), 0, stream>>>(BIG, lrel + (size_t)i * 63 * 8, AOUT);
        gemm(AOUT, projT, lproj_b + i * 512, XL, TMP, nullptr, Btot, 512, 512, 0);
        ln_kernel<<<dim3(Btot / 4), dim3(256), 0, stream>>>(TMP, ln1_g + i * 512, ln1_b + i * 512, XL, (unsigned short*)nullptr);
        dwconv_add_kernel<<<dim3(256, 4), dim3(256), 0, stream>>>(XL, lconv_w + (size_t)i * 512 * 7, lconv_b + i * 512, TMP, XBl);
        gemm(XBl, w1T, lffn_b1 + i * 2048, nullptr, nullptr, BIG, Btot, 2048, 512, 1);
        gemm(BIG, w2T, lffn_b2 + i * 512, TMP, TMP, nullptr, Btot, 512, 2048, 0);
        ln_kernel<<<dim3(Btot / 4), dim3(256), 0, stream>>>(TMP, ln2_g + i * 512, ln2_b + i * 512, XL, XBl);
    }

    // ---------------- global branch: 3 layers ----------------
    for (int i = 0; i < 3; i++) {
        unsigned short* base  = WT + (size_t)(4 + i) * perL;
        unsigned short* qkvT  = base;
        unsigned short* projT = base + 786432;
        unsigned short* w1T   = base + 786432 + 262144;
        unsigned short* w2T   = base + 786432 + 262144 + 1048576;

        gather_xs_kernel<<<dim3(256), dim3(256), 0, stream>>>(XG, XSB);
        gemm(XSB, qkvT, gqkv_b + i * 1536, nullptr, nullptr, GQKV, 512, 1536, 512, 0);
        global_attn_kernel<<<dim3(128), dim3(256), 0, stream>>>(GQKV, GOUT);
        gemm(GOUT, projT, gproj_b + i * 512, nullptr, GA, nullptr, 512, 512, 512, 0);
        interp_ln_kernel<<<dim3(Btot / 4), dim3(256), 0, stream>>>(GA, XG, gn1_g + i * 512, gn1_b + i * 512, XBg);
        gemm(XBg, w1T, gffn_b1 + i * 2048, nullptr, nullptr, BIG, Btot, 2048, 512, 1);
        gemm(BIG, w2T, gffn_b2 + i * 512, XG, TMP, nullptr, Btot, 512, 2048, 0);
        ln_kernel<<<dim3(Btot / 4), dim3(256), 0, stream>>>(TMP, gn2_g + i * 512, gn2_b + i * 512, XG, XBg);
    }

    final_kernel<<<dim3(Btot / 4), dim3(256), 0, stream>>>(XL, XG, fw_local, fw_global, fn_g, fn_b, out);
}